// Round 13
// baseline (341.385 us; speedup 1.0000x reference)
//
#include <hip/hip_runtime.h>
#include <hip/hip_bf16.h>
#include <cstdint>

#define S_SEQ   2048
#define HID     4096
#define NQH     32
#define NKVH    8
#define DH      128
#define QKV_LD  6144      // (32+16)*128
#define SCALE_F 0.08838834764831845f
// softmax in log2 domain: s' = s * SCALE * log2(e)
#define C2F (0.08838834764831845f * 1.4426950408889634f)

using f32x4  = __attribute__((ext_vector_type(4))) float;
using f32x16 = __attribute__((ext_vector_type(16))) float;
using bf16x8 = __attribute__((ext_vector_type(8))) __bf16;
using u32x2  = __attribute__((ext_vector_type(2))) unsigned;

#define GLOAD_LDS16(gp, lp)                                                   \
  __builtin_amdgcn_global_load_lds(                                           \
      (__attribute__((address_space(1))) const void*)(gp),                    \
      (__attribute__((address_space(3))) void*)(lp), 16, 0, 0)

__device__ __forceinline__ unsigned short f2bf_bits(float f) {
  __hip_bfloat16 b = __float2bfloat16(f);
  return __builtin_bit_cast(unsigned short, b);
}

// permlane32_swap: X[32..63] <-> Y[0..31].
__device__ __forceinline__ void plswap(unsigned& x, unsigned& y) {
  u32x2 r = __builtin_amdgcn_permlane32_swap(x, y, false, false);
  x = r[0];
  y = r[1];
}
// value of the partner lane (l ^ 32)
__device__ __forceinline__ float xhalf(float v, int hiP) {
  unsigned u = __builtin_bit_cast(unsigned, v);
  u32x2 r = __builtin_amdgcn_permlane32_swap(u, u, false, false);
  return __builtin_bit_cast(float, hiP ? r[0] : r[1]);
}

// ---------------------------------------------------------------------------
// f32 -> bf16 conversion (vectorized, grid-stride)
// ---------------------------------------------------------------------------
__global__ void cvt_f32_bf16(const float* __restrict__ in,
                             __hip_bfloat16* __restrict__ out, int n) {
  int i = blockIdx.x * blockDim.x + threadIdx.x;
  int stride = gridDim.x * blockDim.x;
  for (int e = i * 4; e < n; e += stride * 4) {
    float4 v = *(const float4*)(in + e);
    ushort4 u;
    u.x = f2bf_bits(v.x); u.y = f2bf_bits(v.y);
    u.z = f2bf_bits(v.z); u.w = f2bf_bits(v.w);
    *reinterpret_cast<ushort4*>(reinterpret_cast<unsigned short*>(out) + e) = u;
  }
}

// ---------------------------------------------------------------------------
// GEMM: C[M,N] = A[M,K] * B[N,K]^T   (both bf16, B^T layout)
// Tile 256M x 128N, BK=32, 4 waves (2x2), per-wave output 128x64
// (FLOP/LDS-read-byte = 43.7 vs 32 at the old 64x64 — LDS BW was the cap).
//  - 3-buffer LDS pipeline, depth-2 prefetch, counted vmcnt(12) (6 ops/stage)
//  - conflict-free LDS slot swizzle (slot ^= (row>>1)&3) via linear LDS dest
//    + inverse-permuted global source (rule #21); 0 conflicts measured
//  - bijective XCD swizzle on flattened wgid (grids are %8 == 0)
// ---------------------------------------------------------------------------
template <bool OUT_BF16>
__global__ __launch_bounds__(256) void gemm_bt_kernel(
    const __hip_bfloat16* __restrict__ A, const __hip_bfloat16* __restrict__ B,
    void* __restrict__ Cv, int M, int N, int K) {
  // per buffer: A 256x32 (8192 el) + B 128x32 (4096 el) = 12288 el (24 KiB)
  __shared__ __hip_bfloat16 sAB[3 * 12288];
  const int tid = threadIdx.x;
  const int w = tid >> 6, l = tid & 63;
  const int wr = w >> 1, wc = w & 1;
  const int lr = l & 15;

  const int nbx = gridDim.x;
  const int nwg = nbx * gridDim.y;
  int wgid = blockIdx.y * nbx + blockIdx.x;
  wgid = (wgid & 7) * (nwg >> 3) + (wgid >> 3);  // XCD chunking
  const int brow = (wgid / nbx) * 256;
  const int bcol = (wgid % nbx) * 128;

  f32x4 acc[8][4];
#pragma unroll
  for (int m = 0; m < 8; m++)
#pragma unroll
    for (int n = 0; n < 4; n++) acc[m][n] = (f32x4){0.f, 0.f, 0.f, 0.f};

  // staging: thread tid -> row tid>>2 within each 64-row group, linear dest;
  // source col permuted so LDS holds slot (tid&3) ^ ((row>>1)&3)
  const int r0 = tid >> 2;
  const int c0s = (((tid & 3) ^ ((tid >> 3) & 3)) << 3);
  const __hip_bfloat16* Ag = A + (size_t)(brow + r0) * K + c0s;
  const __hip_bfloat16* Bg = B + (size_t)(bcol + r0) * K + c0s;

  // read: true k-slot (l>>4) lives at slot (l>>4) ^ ((lr>>1)&3)
  const int sw8 = (((l >> 4) ^ ((lr >> 1) & 3)) << 3);

#define STAGE(BI, K0)                                                         \
  {                                                                           \
    __hip_bfloat16* pa_ = sAB + (BI) * 12288;                                 \
    __hip_bfloat16* pb_ = pa_ + 8192;                                         \
    GLOAD_LDS16(Ag + (K0),                   pa_ + tid * 8);                  \
    GLOAD_LDS16(Ag + (K0) + (size_t)64 * K,  pa_ + 2048 + tid * 8);           \
    GLOAD_LDS16(Ag + (K0) + (size_t)128 * K, pa_ + 4096 + tid * 8);           \
    GLOAD_LDS16(Ag + (K0) + (size_t)192 * K, pa_ + 6144 + tid * 8);           \
    GLOAD_LDS16(Bg + (K0),                   pb_ + tid * 8);                  \
    GLOAD_LDS16(Bg + (K0) + (size_t)64 * K,  pb_ + 2048 + tid * 8);           \
  }

#define COMPUTE(BI)                                                           \
  {                                                                           \
    const __hip_bfloat16* ca_ = sAB + (BI) * 12288;                           \
    const __hip_bfloat16* cb_ = ca_ + 8192;                                   \
    bf16x8 af[8], bfr[4];                                                     \
    _Pragma("unroll") for (int mm = 0; mm < 8; mm++) af[mm] =                 \
        *(const bf16x8*)&ca_[(wr * 128 + mm * 16 + lr) * 32 + sw8];           \
    _Pragma("unroll") for (int nn = 0; nn < 4; nn++) bfr[nn] =                \
        *(const bf16x8*)&cb_[(wc * 64 + nn * 16 + lr) * 32 + sw8];            \
    _Pragma("unroll") for (int mm = 0; mm < 8; mm++)                          \
        _Pragma("unroll") for (int nn = 0; nn < 4; nn++) acc[mm][nn] =        \
        __builtin_amdgcn_mfma_f32_16x16x32_bf16(af[mm], bfr[nn], acc[mm][nn], \
                                                0, 0, 0);                     \
  }

  const int nt = K >> 5;  // K = 4096 -> 128
  STAGE(0, 0);
  STAGE(1, 32);
  int b0 = 0, b1 = 1, b2 = 2;
  for (int t = 0; t < nt - 2; ++t) {
    STAGE(b2, (t + 2) << 5);
    asm volatile("s_waitcnt vmcnt(12)" ::: "memory");
    __builtin_amdgcn_s_barrier();
    __builtin_amdgcn_sched_barrier(0);
    COMPUTE(b0);
    __builtin_amdgcn_s_barrier();
    __builtin_amdgcn_sched_barrier(0);
    int tmp = b0; b0 = b1; b1 = b2; b2 = tmp;
  }
  asm volatile("s_waitcnt vmcnt(6)" ::: "memory");
  __builtin_amdgcn_s_barrier();
  __builtin_amdgcn_sched_barrier(0);
  COMPUTE(b0);
  asm volatile("s_waitcnt vmcnt(0)" ::: "memory");
  __builtin_amdgcn_s_barrier();
  __builtin_amdgcn_sched_barrier(0);
  COMPUTE(b1);
#undef STAGE
#undef COMPUTE

  const int jr = (l >> 4) << 2;
  if (OUT_BF16) {
    __hip_bfloat16* C = (__hip_bfloat16*)Cv;
#pragma unroll
    for (int m = 0; m < 8; m++)
#pragma unroll
      for (int n = 0; n < 4; n++)
#pragma unroll
        for (int j = 0; j < 4; j++) {
          size_t row = brow + wr * 128 + m * 16 + jr + j;
          size_t col = bcol + wc * 64 + n * 16 + lr;
          C[row * N + col] = __float2bfloat16(acc[m][n][j]);
        }
  } else {
    float* C = (float*)Cv;
#pragma unroll
    for (int m = 0; m < 8; m++)
#pragma unroll
      for (int n = 0; n < 4; n++)
#pragma unroll
        for (int j = 0; j < 4; j++) {
          size_t row = brow + wr * 128 + m * 16 + jr + j;
          size_t col = bcol + wc * 64 + n * 16 + lr;
          C[row * N + col] = acc[m][n][j];
        }
  }
}

// ---------------------------------------------------------------------------
// RoPE (neox) in-place on Q (heads 0..31) and K (heads 32..39) of QKV.
// ---------------------------------------------------------------------------
__global__ void rope_kernel(__hip_bfloat16* __restrict__ QKV,
                            const int* __restrict__ pos) {
  int idx = blockIdx.x * blockDim.x + threadIdx.x;  // S*40*64 total
  int d = idx & 63;
  int head = (idx >> 6) % 40;
  int s = idx / (64 * 40);
  float p = (float)pos[s];
  float inv = exp2f(-(float)d * 0.2076205059304297f);
  float fr = p * inv;
  float sn, cs;
  sincosf(fr, &sn, &cs);
  size_t base = (size_t)s * QKV_LD + head * 128 + d;
  float x1 = __bfloat162float(QKV[base]);
  float x2 = __bfloat162float(QKV[base + 64]);
  QKV[base]      = __float2bfloat16(x1 * cs - x2 * sn);
  QKV[base + 64] = __float2bfloat16(x2 * cs + x1 * sn);
}

// ---------------------------------------------------------------------------
// Pack K and V into fragment-ordered buffers so attn loads are coalesced.
//   Kf element (kvh,t,ks,lane,j)       = K[kvh][t*32+(lane&31)][ks*16+(lane>>5)*8+j]
//   Vf element (kvh,t,slot=db*2+k2,lane,j) = V[kvh][t*32+k2*16+(lane>>5)*8+j][db*32+(lane&31)]
// 16B chunk id o: lane=o&63, slot=(o>>6)&7, t=(o>>9)&63, kvh=(o>>15)&7, K/V=o>>18.
// ---------------------------------------------------------------------------
__global__ void packkv_kernel(const __hip_bfloat16* __restrict__ QKV,
                              __hip_bfloat16* __restrict__ Kf,
                              __hip_bfloat16* __restrict__ Vf) {
  int o = blockIdx.x * blockDim.x + threadIdx.x;  // 2 * 2^18 chunks
  const int lane = o & 63;
  const int slot = (o >> 6) & 7;
  const int t    = (o >> 9) & 63;
  const int kvh  = (o >> 15) & 7;
  const int off8 = (o & 0x3FFFF) * 8;
  if (o < (1 << 18)) {
    // K: contiguous 8 along d
    const int s  = t * 32 + (lane & 31);
    const int d0 = slot * 16 + (lane >> 5) * 8;
    bf16x8 v = *(const bf16x8*)(QKV + (size_t)s * QKV_LD + 4096 + kvh * DH + d0);
    *(bf16x8*)(Kf + off8) = v;
  } else {
    // V: gather 8 along s at fixed d (transpose)
    const int s0 = t * 32 + (slot & 1) * 16 + (lane >> 5) * 8;
    const int d  = (slot >> 1) * 32 + (lane & 31);
    const __hip_bfloat16* src = QKV + (size_t)s0 * QKV_LD + 5120 + kvh * DH + d;
    ushort4 a, b;
    a.x = __builtin_bit_cast(unsigned short, src[0 * QKV_LD]);
    a.y = __builtin_bit_cast(unsigned short, src[1 * QKV_LD]);
    a.z = __builtin_bit_cast(unsigned short, src[2 * QKV_LD]);
    a.w = __builtin_bit_cast(unsigned short, src[3 * QKV_LD]);
    b.x = __builtin_bit_cast(unsigned short, src[4 * QKV_LD]);
    b.y = __builtin_bit_cast(unsigned short, src[5 * QKV_LD]);
    b.z = __builtin_bit_cast(unsigned short, src[6 * QKV_LD]);
    b.w = __builtin_bit_cast(unsigned short, src[7 * QKV_LD]);
    *(ushort4*)(Vf + off8)     = a;
    *(ushort4*)(Vf + off8 + 4) = b;
  }
}

// ---------------------------------------------------------------------------
// Causal GQA flash attention (unchanged from R11): swapped-QK 32x32 +
// split-KV x2, coalesced fragment-ordered K/V loads.
// ---------------------------------------------------------------------------
__global__ __launch_bounds__(256, 2) void attn_kernel(
    const __hip_bfloat16* __restrict__ QKV, const __hip_bfloat16* __restrict__ Kf,
    const __hip_bfloat16* __restrict__ Vf, __hip_bfloat16* __restrict__ O) {
  __shared__ float Ms[2][64][67];  // [head-slot][lane][64 oacc + m + lsum]
  const int tid = threadIdx.x;
  const int w = tid >> 6, l = tid & 63;
  const int l31 = l & 31;
  const int hiP = l >> 5;
  const int bid = blockIdx.x;
  const int kvh = bid & 7;                 // XCD-resident kv head
  const int hp = (bid >> 3) & 1;           // head pair within kv group
  const int qt = 63 - (bid >> 4);          // longest blocks dispatched first
  const int half = w >> 1;                 // kv-range half
  const int h = kvh * 4 + hp * 2 + (w & 1);
  const int qwb = qt * 32;                 // q base row
  const int qg = qwb + l31;                // this lane's q row

  const __hip_bfloat16* Qp  = QKV + (size_t)h * DH;
  const __hip_bfloat16* Kfp = Kf + (size_t)kvh * 262144 + l * 8;
  const __hip_bfloat16* Vfp = Vf + (size_t)kvh * 262144 + l * 8;

  // Q B-frags (held whole kernel): qf[ks] = Q[q=l31][ks*16 + hiP*8 .. +8]
  bf16x8 qf[8];
  {
    const __hip_bfloat16* qrow = Qp + (size_t)(qwb + l31) * QKV_LD + hiP * 8;
#pragma unroll
    for (int ks = 0; ks < 8; ks++) qf[ks] = *(const bf16x8*)(qrow + ks * 16);
  }

  f32x16 oacc[4];
#pragma unroll
  for (int db = 0; db < 4; db++)
#pragma unroll
    for (int r = 0; r < 16; r++) oacc[db][r] = 0.f;
  float m = -1e30f, lsum = 0.f;

#define COMPUTE_TILE(KB, MASKED)                                               \
  {                                                                            \
    const int kb_ = (KB);                                                      \
    const int toff_ = (kb_ >> 5) * 4096;                                       \
    f32x16 sacc;                                                               \
    _Pragma("unroll") for (int r = 0; r < 16; r++) sacc[r] = 0.f;              \
    {                                                                          \
      bf16x8 kf[8];                                                            \
      _Pragma("unroll") for (int ks = 0; ks < 8; ks++) kf[ks] =                \
          *(const bf16x8*)(Kfp + toff_ + ks * 512);                            \
      _Pragma("unroll") for (int ks = 0; ks < 8; ks++) sacc =                  \
          __builtin_amdgcn_mfma_f32_32x32x16_bf16(kf[ks], qf[ks], sacc, 0, 0,  \
                                                  0);                          \
    }                                                                          \
    bf16x8 vf[4][2];                                                           \
    _Pragma("unroll") for (int db = 0; db < 4; db++)                           \
        _Pragma("unroll") for (int k2 = 0; k2 < 2; k2++) vf[db][k2] =          \
        *(const bf16x8*)(Vfp + toff_ + (db * 2 + k2) * 512);                   \
    float s[16];                                                               \
    _Pragma("unroll") for (int r = 0; r < 16; r++) s[r] = sacc[r] * C2F;       \
    if (MASKED) {                                                              \
      _Pragma("unroll") for (int r = 0; r < 16; r++) {                         \
        const int kvg = kb_ + (r & 3) + 8 * (r >> 2) + 4 * hiP;                \
        s[r] = (kvg <= qg) ? s[r] : -1e30f;                                    \
      }                                                                        \
    }                                                                          \
    float m0 = fmaxf(fmaxf(s[0], s[1]), fmaxf(s[2], s[3]));                    \
    float m1 = fmaxf(fmaxf(s[4], s[5]), fmaxf(s[6], s[7]));                    \
    float m2 = fmaxf(fmaxf(s[8], s[9]), fmaxf(s[10], s[11]));                  \
    float m3 = fmaxf(fmaxf(s[12], s[13]), fmaxf(s[14], s[15]));                \
    float rmax = fmaxf(fmaxf(m0, m1), fmaxf(m2, m3));                          \
    rmax = fmaxf(rmax, xhalf(rmax, hiP));                                      \
    if (__any(rmax - m > 8.0f)) {                                              \
      float mn = fmaxf(m, rmax);                                               \
      float sc = __builtin_amdgcn_exp2f(m - mn);                               \
      lsum *= sc;                                                              \
      _Pragma("unroll") for (int db = 0; db < 4; db++)                         \
          _Pragma("unroll") for (int r = 0; r < 16; r++) oacc[db][r] *= sc;    \
      m = mn;                                                                  \
    }                                                                          \
    float p[16];                                                               \
    _Pragma("unroll") for (int r = 0; r < 16; r++) p[r] =                      \
        __builtin_amdgcn_exp2f(s[r] - m);                                      \
    float rs = ((p[0] + p[1]) + (p[2] + p[3])) +                               \
               ((p[4] + p[5]) + (p[6] + p[7])) +                               \
               ((p[8] + p[9]) + (p[10] + p[11])) +                             \
               ((p[12] + p[13]) + (p[14] + p[15]));                            \
    lsum += rs + xhalf(rs, hiP);                                               \
    unsigned Wp[8];                                                            \
    _Pragma("unroll") for (int i = 0; i < 8; i++) Wp[i] =                      \
        (unsigned)f2bf_bits(p[2 * i]) |                                        \
        ((unsigned)f2bf_bits(p[2 * i + 1]) << 16);                             \
    unsigned s0x = Wp[0], s0y = Wp[2];                                         \
    unsigned s1x = Wp[1], s1y = Wp[3];                                         \
    unsigned s2x = Wp[4], s2y = Wp[6];                                         \
    unsigned s3x = Wp[5], s3y = Wp[7];                                         \
    plswap(s0x, s0y);                                                          \
    plswap(s1x, s1y);                                                          \
    plswap(s2x, s2y);                                                          \
    plswap(s3x, s3y);                                                          \
    int4 f0, f1;                                                               \
    f0.x = (int)s0x; f0.y = (int)s1x; f0.z = (int)s0y; f0.w = (int)s1y;        \
    f1.x = (int)s2x; f1.y = (int)s3x; f1.z = (int)s2y; f1.w = (int)s3y;        \
    bf16x8 pfrag[2];                                                           \
    pfrag[0] = __builtin_bit_cast(bf16x8, f0);                                 \
    pfrag[1] = __builtin_bit_cast(bf16x8, f1);                                 \
    _Pragma("unroll") for (int db = 0; db < 4; db++)                           \
        _Pragma("unroll") for (int k2 = 0; k2 < 2; k2++) oacc[db] =            \
        __builtin_amdgcn_mfma_f32_32x32x16_bf16(vf[db][k2], pfrag[k2],         \
                                                oacc[db], 0, 0, 0);            \
  }

  const int nt = qt + 1;
  const int nt0 = nt >> 1;  // tiles in half 0 (may be 0)

  if (half) {
    for (int kb = nt0 * 32; kb < qwb; kb += 32) COMPUTE_TILE(kb, false);
    COMPUTE_TILE(qwb, true);
  } else {
    const int kend = nt0 * 32;
    for (int kb = 0; kb < kend; kb += 32) COMPUTE_TILE(kb, false);
  }
#undef COMPUTE_TILE

  // ---- split-KV merge ----
  if (half) {
    float* dst = Ms[w & 1][l];
#pragma unroll
    for (int db = 0; db < 4; db++)
#pragma unroll
      for (int r = 0; r < 16; r++) dst[db * 16 + r] = oacc[db][r];
    dst[64] = m;
    dst[65] = lsum;
  }
  __syncthreads();
  if (!half) {
    const float* src = Ms[w & 1][l];
    const float mB = src[64], lB = src[65];
    const float mS = fmaxf(m, mB);
    float fa = __builtin_amdgcn_exp2f(m - mS);
    float fb = __builtin_amdgcn_exp2f(mB - mS);
    const float inv = 1.0f / (lsum * fa + lB * fb);
    fa *= inv;
    fb *= inv;
    // write O[q][h*128 + d], d = db*32 + 8*rg + 4*hiP + (r&3)
    __hip_bfloat16* orow = O + (size_t)qg * (NQH * DH) + h * DH;
#pragma unroll
    for (int db = 0; db < 4; db++)
#pragma unroll
      for (int rg = 0; rg < 4; rg++) {
        ushort4 u;
        u.x = f2bf_bits(oacc[db][rg * 4 + 0] * fa + src[db * 16 + rg * 4 + 0] * fb);
        u.y = f2bf_bits(oacc[db][rg * 4 + 1] * fa + src[db * 16 + rg * 4 + 1] * fb);
        u.z = f2bf_bits(oacc[db][rg * 4 + 2] * fa + src[db * 16 + rg * 4 + 2] * fb);
        u.w = f2bf_bits(oacc[db][rg * 4 + 3] * fa + src[db * 16 + rg * 4 + 3] * fb);
        *reinterpret_cast<ushort4*>(orow + db * 32 + 8 * rg + 4 * hiP) = u;
      }
  }
}

// ---------------------------------------------------------------------------
extern "C" void kernel_launch(void* const* d_in, const int* in_sizes, int n_in,
                              void* d_out, int out_size, void* d_ws,
                              size_t ws_size, hipStream_t stream) {
  const float* hs = (const float*)d_in[0];
  const int* pos = (const int*)d_in[1];
  const float* wqkv = (const float*)d_in[2];
  const float* wo = (const float*)d_in[3];
  float* out = (float*)d_out;

  char* ws = (char*)d_ws;
  __hip_bfloat16* Xb      = (__hip_bfloat16*)(ws);                // 16 MB
  __hip_bfloat16* Wqkvb   = (__hip_bfloat16*)(ws + 16777216);     // 48 MB
  __hip_bfloat16* Wob     = (__hip_bfloat16*)(ws + 67108864);     // 32 MB
  __hip_bfloat16* QKV     = (__hip_bfloat16*)(ws + 100663296);    // 24 MB
  __hip_bfloat16* AttnOut = (__hip_bfloat16*)(ws + 125829120);    // 16 MB
  __hip_bfloat16* Kf      = (__hip_bfloat16*)(ws + 142606336);    // 4 MB
  __hip_bfloat16* Vf      = (__hip_bfloat16*)(ws);                // 4 MB (Xb dead after gemm1)

  cvt_f32_bf16<<<2048, 256, 0, stream>>>(hs, Xb, S_SEQ * HID);
  cvt_f32_bf16<<<2048, 256, 0, stream>>>(wqkv, Wqkvb, QKV_LD * HID);
  cvt_f32_bf16<<<2048, 256, 0, stream>>>(wo, Wob, HID * HID);

  gemm_bt_kernel<true><<<dim3(QKV_LD / 128, S_SEQ / 256), 256, 0, stream>>>(
      Xb, Wqkvb, QKV, S_SEQ, QKV_LD, HID);

  rope_kernel<<<(S_SEQ * 40 * 64) / 256, 256, 0, stream>>>(QKV, pos);
  packkv_kernel<<<2048, 256, 0, stream>>>(QKV, Kf, Vf);

  attn_kernel<<<1024, 256, 0, stream>>>(QKV, Kf, Vf, AttnOut);

  gemm_bt_kernel<false><<<dim3(HID / 128, S_SEQ / 256), 256, 0, stream>>>(
      AttnOut, Wob, out, S_SEQ, HID, HID);
}

// Round 14
// 337.058 us; speedup vs baseline: 1.0128x; 1.0128x over previous
//
#include <hip/hip_runtime.h>
#include <hip/hip_bf16.h>
#include <cstdint>

#define S_SEQ   2048
#define HID     4096
#define NQH     32
#define NKVH    8
#define DH      128
#define QKV_LD  6144      // (32+16)*128
#define SCALE_F 0.08838834764831845f
// softmax in log2 domain: s' = s * SCALE * log2(e)
#define C2F (0.08838834764831845f * 1.4426950408889634f)

using f32x4  = __attribute__((ext_vector_type(4))) float;
using f32x16 = __attribute__((ext_vector_type(16))) float;
using bf16x8 = __attribute__((ext_vector_type(8))) __bf16;
using u32x2  = __attribute__((ext_vector_type(2))) unsigned;

#define GLOAD_LDS16(gp, lp)                                                   \
  __builtin_amdgcn_global_load_lds(                                           \
      (__attribute__((address_space(1))) const void*)(gp),                    \
      (__attribute__((address_space(3))) void*)(lp), 16, 0, 0)

__device__ __forceinline__ unsigned short f2bf_bits(float f) {
  __hip_bfloat16 b = __float2bfloat16(f);
  return __builtin_bit_cast(unsigned short, b);
}

// permlane32_swap: X[32..63] <-> Y[0..31].
__device__ __forceinline__ void plswap(unsigned& x, unsigned& y) {
  u32x2 r = __builtin_amdgcn_permlane32_swap(x, y, false, false);
  x = r[0];
  y = r[1];
}
// value of the partner lane (l ^ 32)
__device__ __forceinline__ float xhalf(float v, int hiP) {
  unsigned u = __builtin_bit_cast(unsigned, v);
  u32x2 r = __builtin_amdgcn_permlane32_swap(u, u, false, false);
  return __builtin_bit_cast(float, hiP ? r[0] : r[1]);
}

// ---------------------------------------------------------------------------
// f32 -> bf16 conversion (vectorized, grid-stride)
// ---------------------------------------------------------------------------
__global__ void cvt_f32_bf16(const float* __restrict__ in,
                             __hip_bfloat16* __restrict__ out, int n) {
  int i = blockIdx.x * blockDim.x + threadIdx.x;
  int stride = gridDim.x * blockDim.x;
  for (int e = i * 4; e < n; e += stride * 4) {
    float4 v = *(const float4*)(in + e);
    ushort4 u;
    u.x = f2bf_bits(v.x); u.y = f2bf_bits(v.y);
    u.z = f2bf_bits(v.z); u.w = f2bf_bits(v.w);
    *reinterpret_cast<ushort4*>(reinterpret_cast<unsigned short*>(out) + e) = u;
  }
}

// ---------------------------------------------------------------------------
// GEMM: C[M,N] = A[M,K] * B[N,K]^T   (both bf16, B^T layout)
// 256x256 tile, BK=64, 8 waves (2Mx4N), 512 threads; multi-phase schedule:
//  - K-tile split into 2 half-tiles by k-slice (ks=0/1); LDS double-buffered:
//    per buf A[2][256][32] + B[2][256][32] (64 KiB), 2 bufs = 128 KiB dynamic
//  - tile t+1's 8 stage-issues are spread across tile t's phases, ordered
//    {A-ks0,B-ks0,A-ks1,B-ks1}; each half-tile barrier uses counted vmcnt(4)
//    (oldest half-tile complete) — never vmcnt(0) except the final tile
//  - s_setprio(1) around each 16-MFMA cluster (T5)
//  - slot swizzle (slot ^= (row>>1)&3): linear LDS dest + inverse-permuted
//    global source (rule #21); measured 0 conflicts in this algebra
//  - bijective XCD swizzle on flattened wgid (grids are %8 == 0)
// ---------------------------------------------------------------------------
template <bool OUT_BF16>
__global__ __launch_bounds__(512) void gemm_bt_kernel(
    const __hip_bfloat16* __restrict__ A, const __hip_bfloat16* __restrict__ B,
    void* __restrict__ Cv, int M, int N, int K) {
  extern __shared__ __hip_bfloat16 sAB[];  // [2][32768] elements
  const int tid = threadIdx.x;
  const int w = tid >> 6, l = tid & 63;
  const int wm = w >> 2, wn = w & 3;
  const int lr = l & 15;

  const int nbx = gridDim.x;
  const int nwg = nbx * gridDim.y;
  int wgid = blockIdx.y * nbx + blockIdx.x;
  wgid = (wgid & 7) * (nwg >> 3) + (wgid >> 3);  // XCD chunking
  const int brow = (wgid / nbx) * 256;
  const int bcol = (wgid % nbx) * 256;

  f32x4 acc[8][4];
#pragma unroll
  for (int m = 0; m < 8; m++)
#pragma unroll
    for (int n = 0; n < 4; n++) acc[m][n] = (f32x4){0.f, 0.f, 0.f, 0.f};

  // staging: 512 threads cover 128 rows x 4 slots per issue (linear LDS dest);
  // source col8 permuted so LDS slot p holds global slot p ^ ((row>>1)&3)
  const int r0 = tid >> 2;                                  // 0..127
  const int c0s = (((tid & 3) ^ ((tid >> 3) & 3)) << 3);    // elements
  const __hip_bfloat16* Ag = A + (size_t)(brow + r0) * K + c0s;
  const __hip_bfloat16* Bg = B + (size_t)(bcol + r0) * K + c0s;
  const int ldst = tid * 8;

  // read: logical slot (l>>4) lives at slot (l>>4) ^ ((lr>>1)&3)
  const int sw8 = (((l >> 4) ^ ((lr >> 1) & 3)) << 3);

#define STG_A(BUF, K0, KS, RB)                                                \
  GLOAD_LDS16(Ag + (K0) + (KS) * 32 + (size_t)((RB) * 128) * K,               \
              sAB + (BUF) * 32768 + (KS) * 8192 + (RB) * 4096 + ldst)
#define STG_B(BUF, K0, KS, RB)                                                \
  GLOAD_LDS16(Bg + (K0) + (KS) * 32 + (size_t)((RB) * 128) * K,               \
              sAB + (BUF) * 32768 + 16384 + (KS) * 8192 + (RB) * 4096 + ldst)

// one n-pair cluster: reads bfr[2], 16 MFMAs into acc[.][NP*2+j]
#define CLUSTER(BB, NP)                                                       \
  {                                                                           \
    bf16x8 bfr[2];                                                            \
    _Pragma("unroll") for (int j = 0; j < 2; j++) bfr[j] =                    \
        *(const bf16x8*)&(BB)[(wn * 64 + ((NP)*2 + j) * 16 + lr) * 32 + sw8]; \
    __builtin_amdgcn_s_setprio(1);                                            \
    _Pragma("unroll") for (int mm = 0; mm < 8; mm++)                          \
        _Pragma("unroll") for (int j = 0; j < 2; j++)                         \
        acc[mm][(NP)*2 + j] = __builtin_amdgcn_mfma_f32_16x16x32_bf16(        \
            af[mm], bfr[j], acc[mm][(NP)*2 + j], 0, 0, 0);                    \
    __builtin_amdgcn_s_setprio(0);                                            \
  }

  const int nt = K >> 6;  // K-tiles of 64
  // prologue: stage tile 0 into buffer 0, half-tile order ks0 then ks1
  STG_A(0, 0, 0, 0); STG_A(0, 0, 0, 1);
  STG_B(0, 0, 0, 0); STG_B(0, 0, 0, 1);
  STG_A(0, 0, 1, 0); STG_A(0, 0, 1, 1);
  STG_B(0, 0, 1, 0); STG_B(0, 0, 1, 1);

  for (int t = 0; t < nt; ++t) {
    const int buf = t & 1, nb = buf ^ 1;
    const int k1 = (t + 1) << 6;
    const bool hn = (t + 1) < nt;
    const __hip_bfloat16* ab0 = sAB + buf * 32768;
    const __hip_bfloat16* bb0 = ab0 + 16384;

    // ---- half-tile ks=0 ----  (its 4 loads are the oldest outstanding)
    asm volatile("s_waitcnt vmcnt(4)" ::: "memory");
    __builtin_amdgcn_s_barrier();
    __builtin_amdgcn_sched_barrier(0);
    if (hn) { STG_A(nb, k1, 0, 0); STG_A(nb, k1, 0, 1); }
    {
      bf16x8 af[8];
#pragma unroll
      for (int mm = 0; mm < 8; mm++)
        af[mm] = *(const bf16x8*)&ab0[(wm * 128 + mm * 16 + lr) * 32 + sw8];
      CLUSTER(bb0, 0);
      if (hn) { STG_B(nb, k1, 0, 0); STG_B(nb, k1, 0, 1); }
      CLUSTER(bb0, 1);
    }
    // ---- half-tile ks=1 ----
    if (hn) {
      asm volatile("s_waitcnt vmcnt(4)" ::: "memory");
    } else {
      asm volatile("s_waitcnt vmcnt(0)" ::: "memory");
    }
    __builtin_amdgcn_s_barrier();
    __builtin_amdgcn_sched_barrier(0);
    if (hn) { STG_A(nb, k1, 1, 0); STG_A(nb, k1, 1, 1); }
    {
      const __hip_bfloat16* ab1 = ab0 + 8192;
      const __hip_bfloat16* bb1 = bb0 + 8192;
      bf16x8 af[8];
#pragma unroll
      for (int mm = 0; mm < 8; mm++)
        af[mm] = *(const bf16x8*)&ab1[(wm * 128 + mm * 16 + lr) * 32 + sw8];
      CLUSTER(bb1, 0);
      if (hn) { STG_B(nb, k1, 1, 0); STG_B(nb, k1, 1, 1); }
      CLUSTER(bb1, 1);
    }
  }
#undef STG_A
#undef STG_B
#undef CLUSTER

  const int jr = (l >> 4) << 2;
  if (OUT_BF16) {
    __hip_bfloat16* C = (__hip_bfloat16*)Cv;
#pragma unroll
    for (int m = 0; m < 8; m++)
#pragma unroll
      for (int n = 0; n < 4; n++)
#pragma unroll
        for (int j = 0; j < 4; j++) {
          size_t row = brow + wm * 128 + m * 16 + jr + j;
          size_t col = bcol + wn * 64 + n * 16 + lr;
          C[row * N + col] = __float2bfloat16(acc[m][n][j]);
        }
  } else {
    float* C = (float*)Cv;
#pragma unroll
    for (int m = 0; m < 8; m++)
#pragma unroll
      for (int n = 0; n < 4; n++)
#pragma unroll
        for (int j = 0; j < 4; j++) {
          size_t row = brow + wm * 128 + m * 16 + jr + j;
          size_t col = bcol + wn * 64 + n * 16 + lr;
          C[row * N + col] = acc[m][n][j];
        }
  }
}

// ---------------------------------------------------------------------------
// RoPE (neox) in-place on Q (heads 0..31) and K (heads 32..39) of QKV.
// ---------------------------------------------------------------------------
__global__ void rope_kernel(__hip_bfloat16* __restrict__ QKV,
                            const int* __restrict__ pos) {
  int idx = blockIdx.x * blockDim.x + threadIdx.x;  // S*40*64 total
  int d = idx & 63;
  int head = (idx >> 6) % 40;
  int s = idx / (64 * 40);
  float p = (float)pos[s];
  float inv = exp2f(-(float)d * 0.2076205059304297f);
  float fr = p * inv;
  float sn, cs;
  sincosf(fr, &sn, &cs);
  size_t base = (size_t)s * QKV_LD + head * 128 + d;
  float x1 = __bfloat162float(QKV[base]);
  float x2 = __bfloat162float(QKV[base + 64]);
  QKV[base]      = __float2bfloat16(x1 * cs - x2 * sn);
  QKV[base + 64] = __float2bfloat16(x2 * cs + x1 * sn);
}

// ---------------------------------------------------------------------------
// Pack K and V into fragment-ordered buffers so attn loads are coalesced.
//   Kf element (kvh,t,ks,lane,j)       = K[kvh][t*32+(lane&31)][ks*16+(lane>>5)*8+j]
//   Vf element (kvh,t,slot=db*2+k2,lane,j) = V[kvh][t*32+k2*16+(lane>>5)*8+j][db*32+(lane&31)]
// 16B chunk id o: lane=o&63, slot=(o>>6)&7, t=(o>>9)&63, kvh=(o>>15)&7, K/V=o>>18.
// ---------------------------------------------------------------------------
__global__ void packkv_kernel(const __hip_bfloat16* __restrict__ QKV,
                              __hip_bfloat16* __restrict__ Kf,
                              __hip_bfloat16* __restrict__ Vf) {
  int o = blockIdx.x * blockDim.x + threadIdx.x;  // 2 * 2^18 chunks
  const int lane = o & 63;
  const int slot = (o >> 6) & 7;
  const int t    = (o >> 9) & 63;
  const int kvh  = (o >> 15) & 7;
  const int off8 = (o & 0x3FFFF) * 8;
  if (o < (1 << 18)) {
    // K: contiguous 8 along d
    const int s  = t * 32 + (lane & 31);
    const int d0 = slot * 16 + (lane >> 5) * 8;
    bf16x8 v = *(const bf16x8*)(QKV + (size_t)s * QKV_LD + 4096 + kvh * DH + d0);
    *(bf16x8*)(Kf + off8) = v;
  } else {
    // V: gather 8 along s at fixed d (transpose)
    const int s0 = t * 32 + (slot & 1) * 16 + (lane >> 5) * 8;
    const int d  = (slot >> 1) * 32 + (lane & 31);
    const __hip_bfloat16* src = QKV + (size_t)s0 * QKV_LD + 5120 + kvh * DH + d;
    ushort4 a, b;
    a.x = __builtin_bit_cast(unsigned short, src[0 * QKV_LD]);
    a.y = __builtin_bit_cast(unsigned short, src[1 * QKV_LD]);
    a.z = __builtin_bit_cast(unsigned short, src[2 * QKV_LD]);
    a.w = __builtin_bit_cast(unsigned short, src[3 * QKV_LD]);
    b.x = __builtin_bit_cast(unsigned short, src[4 * QKV_LD]);
    b.y = __builtin_bit_cast(unsigned short, src[5 * QKV_LD]);
    b.z = __builtin_bit_cast(unsigned short, src[6 * QKV_LD]);
    b.w = __builtin_bit_cast(unsigned short, src[7 * QKV_LD]);
    *(ushort4*)(Vf + off8)     = a;
    *(ushort4*)(Vf + off8 + 4) = b;
  }
}

// ---------------------------------------------------------------------------
// Causal GQA flash attention (unchanged from R11): swapped-QK 32x32 +
// split-KV x2, coalesced fragment-ordered K/V loads.
// ---------------------------------------------------------------------------
__global__ __launch_bounds__(256, 2) void attn_kernel(
    const __hip_bfloat16* __restrict__ QKV, const __hip_bfloat16* __restrict__ Kf,
    const __hip_bfloat16* __restrict__ Vf, __hip_bfloat16* __restrict__ O) {
  __shared__ float Ms[2][64][67];  // [head-slot][lane][64 oacc + m + lsum]
  const int tid = threadIdx.x;
  const int w = tid >> 6, l = tid & 63;
  const int l31 = l & 31;
  const int hiP = l >> 5;
  const int bid = blockIdx.x;
  const int kvh = bid & 7;                 // XCD-resident kv head
  const int hp = (bid >> 3) & 1;           // head pair within kv group
  const int qt = 63 - (bid >> 4);          // longest blocks dispatched first
  const int half = w >> 1;                 // kv-range half
  const int h = kvh * 4 + hp * 2 + (w & 1);
  const int qwb = qt * 32;                 // q base row
  const int qg = qwb + l31;                // this lane's q row

  const __hip_bfloat16* Qp  = QKV + (size_t)h * DH;
  const __hip_bfloat16* Kfp = Kf + (size_t)kvh * 262144 + l * 8;
  const __hip_bfloat16* Vfp = Vf + (size_t)kvh * 262144 + l * 8;

  // Q B-frags (held whole kernel): qf[ks] = Q[q=l31][ks*16 + hiP*8 .. +8]
  bf16x8 qf[8];
  {
    const __hip_bfloat16* qrow = Qp + (size_t)(qwb + l31) * QKV_LD + hiP * 8;
#pragma unroll
    for (int ks = 0; ks < 8; ks++) qf[ks] = *(const bf16x8*)(qrow + ks * 16);
  }

  f32x16 oacc[4];
#pragma unroll
  for (int db = 0; db < 4; db++)
#pragma unroll
    for (int r = 0; r < 16; r++) oacc[db][r] = 0.f;
  float m = -1e30f, lsum = 0.f;

#define COMPUTE_TILE(KB, MASKED)                                               \
  {                                                                            \
    const int kb_ = (KB);                                                      \
    const int toff_ = (kb_ >> 5) * 4096;                                       \
    f32x16 sacc;                                                               \
    _Pragma("unroll") for (int r = 0; r < 16; r++) sacc[r] = 0.f;              \
    {                                                                          \
      bf16x8 kf[8];                                                            \
      _Pragma("unroll") for (int ks = 0; ks < 8; ks++) kf[ks] =                \
          *(const bf16x8*)(Kfp + toff_ + ks * 512);                            \
      _Pragma("unroll") for (int ks = 0; ks < 8; ks++) sacc =                  \
          __builtin_amdgcn_mfma_f32_32x32x16_bf16(kf[ks], qf[ks], sacc, 0, 0,  \
                                                  0);                          \
    }                                                                          \
    bf16x8 vf[4][2];                                                           \
    _Pragma("unroll") for (int db = 0; db < 4; db++)                           \
        _Pragma("unroll") for (int k2 = 0; k2 < 2; k2++) vf[db][k2] =          \
        *(const bf16x8*)(Vfp + toff_ + (db * 2 + k2) * 512);                   \
    float s[16];                                                               \
    _Pragma("unroll") for (int r = 0; r < 16; r++) s[r] = sacc[r] * C2F;       \
    if (MASKED) {                                                              \
      _Pragma("unroll") for (int r = 0; r < 16; r++) {                         \
        const int kvg = kb_ + (r & 3) + 8 * (r >> 2) + 4 * hiP;                \
        s[r] = (kvg <= qg) ? s[r] : -1e30f;                                    \
      }                                                                        \
    }                                                                          \
    float m0 = fmaxf(fmaxf(s[0], s[1]), fmaxf(s[2], s[3]));                    \
    float m1 = fmaxf(fmaxf(s[4], s[5]), fmaxf(s[6], s[7]));                    \
    float m2 = fmaxf(fmaxf(s[8], s[9]), fmaxf(s[10], s[11]));                  \
    float m3 = fmaxf(fmaxf(s[12], s[13]), fmaxf(s[14], s[15]));                \
    float rmax = fmaxf(fmaxf(m0, m1), fmaxf(m2, m3));                          \
    rmax = fmaxf(rmax, xhalf(rmax, hiP));                                      \
    if (__any(rmax - m > 8.0f)) {                                              \
      float mn = fmaxf(m, rmax);                                               \
      float sc = __builtin_amdgcn_exp2f(m - mn);                               \
      lsum *= sc;                                                              \
      _Pragma("unroll") for (int db = 0; db < 4; db++)                         \
          _Pragma("unroll") for (int r = 0; r < 16; r++) oacc[db][r] *= sc;    \
      m = mn;                                                                  \
    }                                                                          \
    float p[16];                                                               \
    _Pragma("unroll") for (int r = 0; r < 16; r++) p[r] =                      \
        __builtin_amdgcn_exp2f(s[r] - m);                                      \
    float rs = ((p[0] + p[1]) + (p[2] + p[3])) +                               \
               ((p[4] + p[5]) + (p[6] + p[7])) +                               \
               ((p[8] + p[9]) + (p[10] + p[11])) +                             \
               ((p[12] + p[13]) + (p[14] + p[15]));                            \
    lsum += rs + xhalf(rs, hiP);                                               \
    unsigned Wp[8];                                                            \
    _Pragma("unroll") for (int i = 0; i < 8; i++) Wp[i] =                      \
        (unsigned)f2bf_bits(p[2 * i]) |                                        \
        ((unsigned)f2bf_bits(p[2 * i + 1]) << 16);                             \
    unsigned s0x = Wp[0], s0y = Wp[2];                                         \
    unsigned s1x = Wp[1], s1y = Wp[3];                                         \
    unsigned s2x = Wp[4], s2y = Wp[6];                                         \
    unsigned s3x = Wp[5], s3y = Wp[7];                                         \
    plswap(s0x, s0y);                                                          \
    plswap(s1x, s1y);                                                          \
    plswap(s2x, s2y);                                                          \
    plswap(s3x, s3y);                                                          \
    int4 f0, f1;                                                               \
    f0.x = (int)s0x; f0.y = (int)s1x; f0.z = (int)s0y; f0.w = (int)s1y;        \
    f1.x = (int)s2x; f1.y = (int)s3x; f1.z = (int)s2y; f1.w = (int)s3y;        \
    bf16x8 pfrag[2];                                                           \
    pfrag[0] = __builtin_bit_cast(bf16x8, f0);                                 \
    pfrag[1] = __builtin_bit_cast(bf16x8, f1);                                 \
    _Pragma("unroll") for (int db = 0; db < 4; db++)                           \
        _Pragma("unroll") for (int k2 = 0; k2 < 2; k2++) oacc[db] =            \
        __builtin_amdgcn_mfma_f32_32x32x16_bf16(vf[db][k2], pfrag[k2],         \
                                                oacc[db], 0, 0, 0);            \
  }

  const int nt = qt + 1;
  const int nt0 = nt >> 1;  // tiles in half 0 (may be 0)

  if (half) {
    for (int kb = nt0 * 32; kb < qwb; kb += 32) COMPUTE_TILE(kb, false);
    COMPUTE_TILE(qwb, true);
  } else {
    const int kend = nt0 * 32;
    for (int kb = 0; kb < kend; kb += 32) COMPUTE_TILE(kb, false);
  }
#undef COMPUTE_TILE

  // ---- split-KV merge ----
  if (half) {
    float* dst = Ms[w & 1][l];
#pragma unroll
    for (int db = 0; db < 4; db++)
#pragma unroll
      for (int r = 0; r < 16; r++) dst[db * 16 + r] = oacc[db][r];
    dst[64] = m;
    dst[65] = lsum;
  }
  __syncthreads();
  if (!half) {
    const float* src = Ms[w & 1][l];
    const float mB = src[64], lB = src[65];
    const float mS = fmaxf(m, mB);
    float fa = __builtin_amdgcn_exp2f(m - mS);
    float fb = __builtin_amdgcn_exp2f(mB - mS);
    const float inv = 1.0f / (lsum * fa + lB * fb);
    fa *= inv;
    fb *= inv;
    // write O[q][h*128 + d], d = db*32 + 8*rg + 4*hiP + (r&3)
    __hip_bfloat16* orow = O + (size_t)qg * (NQH * DH) + h * DH;
#pragma unroll
    for (int db = 0; db < 4; db++)
#pragma unroll
      for (int rg = 0; rg < 4; rg++) {
        ushort4 u;
        u.x = f2bf_bits(oacc[db][rg * 4 + 0] * fa + src[db * 16 + rg * 4 + 0] * fb);
        u.y = f2bf_bits(oacc[db][rg * 4 + 1] * fa + src[db * 16 + rg * 4 + 1] * fb);
        u.z = f2bf_bits(oacc[db][rg * 4 + 2] * fa + src[db * 16 + rg * 4 + 2] * fb);
        u.w = f2bf_bits(oacc[db][rg * 4 + 3] * fa + src[db * 16 + rg * 4 + 3] * fb);
        *reinterpret_cast<ushort4*>(orow + db * 32 + 8 * rg + 4 * hiP) = u;
      }
  }
}

// ---------------------------------------------------------------------------
extern "C" void kernel_launch(void* const* d_in, const int* in_sizes, int n_in,
                              void* d_out, int out_size, void* d_ws,
                              size_t ws_size, hipStream_t stream) {
  const float* hs = (const float*)d_in[0];
  const int* pos = (const int*)d_in[1];
  const float* wqkv = (const float*)d_in[2];
  const float* wo = (const float*)d_in[3];
  float* out = (float*)d_out;

  char* ws = (char*)d_ws;
  __hip_bfloat16* Xb      = (__hip_bfloat16*)(ws);                // 16 MB
  __hip_bfloat16* Wqkvb   = (__hip_bfloat16*)(ws + 16777216);     // 48 MB
  __hip_bfloat16* Wob     = (__hip_bfloat16*)(ws + 67108864);     // 32 MB
  __hip_bfloat16* QKV     = (__hip_bfloat16*)(ws + 100663296);    // 24 MB
  __hip_bfloat16* AttnOut = (__hip_bfloat16*)(ws + 125829120);    // 16 MB
  __hip_bfloat16* Kf      = (__hip_bfloat16*)(ws + 142606336);    // 4 MB
  __hip_bfloat16* Vf      = (__hip_bfloat16*)(ws);                // 4 MB (Xb dead after gemm1)

  cvt_f32_bf16<<<2048, 256, 0, stream>>>(hs, Xb, S_SEQ * HID);
  cvt_f32_bf16<<<2048, 256, 0, stream>>>(wqkv, Wqkvb, QKV_LD * HID);
  cvt_f32_bf16<<<2048, 256, 0, stream>>>(wo, Wob, HID * HID);

  gemm_bt_kernel<true><<<dim3(QKV_LD / 256, S_SEQ / 256), 512, 131072, stream>>>(
      Xb, Wqkvb, QKV, S_SEQ, QKV_LD, HID);

  rope_kernel<<<(S_SEQ * 40 * 64) / 256, 256, 0, stream>>>(QKV, pos);
  packkv_kernel<<<2048, 256, 0, stream>>>(QKV, Kf, Vf);

  attn_kernel<<<1024, 256, 0, stream>>>(QKV, Kf, Vf, AttnOut);

  gemm_bt_kernel<false><<<dim3(HID / 256, S_SEQ / 256), 512, 131072, stream>>>(
      AttnOut, Wob, out, S_SEQ, HID, HID);
}

// Round 15
// 313.292 us; speedup vs baseline: 1.0897x; 1.0759x over previous
//
#include <hip/hip_runtime.h>
#include <hip/hip_bf16.h>
#include <cstdint>

#define S_SEQ   2048
#define HID     4096
#define NQH     32
#define NKVH    8
#define DH      128
#define QKV_LD  6144      // (32+16)*128
#define SCALE_F 0.08838834764831845f
// softmax in log2 domain: s' = s * SCALE * log2(e)
#define C2F (0.08838834764831845f * 1.4426950408889634f)

using f32x4  = __attribute__((ext_vector_type(4))) float;
using f32x16 = __attribute__((ext_vector_type(16))) float;
using bf16x8 = __attribute__((ext_vector_type(8))) __bf16;
using u32x2  = __attribute__((ext_vector_type(2))) unsigned;

#define GLOAD_LDS16(gp, lp)                                                   \
  __builtin_amdgcn_global_load_lds(                                           \
      (__attribute__((address_space(1))) const void*)(gp),                    \
      (__attribute__((address_space(3))) void*)(lp), 16, 0, 0)

__device__ __forceinline__ unsigned short f2bf_bits(float f) {
  __hip_bfloat16 b = __float2bfloat16(f);
  return __builtin_bit_cast(unsigned short, b);
}

// permlane32_swap: X[32..63] <-> Y[0..31].
__device__ __forceinline__ void plswap(unsigned& x, unsigned& y) {
  u32x2 r = __builtin_amdgcn_permlane32_swap(x, y, false, false);
  x = r[0];
  y = r[1];
}
// value of the partner lane (l ^ 32)
__device__ __forceinline__ float xhalf(float v, int hiP) {
  unsigned u = __builtin_bit_cast(unsigned, v);
  u32x2 r = __builtin_amdgcn_permlane32_swap(u, u, false, false);
  return __builtin_bit_cast(float, hiP ? r[0] : r[1]);
}

// ---------------------------------------------------------------------------
// f32 -> bf16 conversion (vectorized, grid-stride)
// ---------------------------------------------------------------------------
__global__ void cvt_f32_bf16(const float* __restrict__ in,
                             __hip_bfloat16* __restrict__ out, int n) {
  int i = blockIdx.x * blockDim.x + threadIdx.x;
  int stride = gridDim.x * blockDim.x;
  for (int e = i * 4; e < n; e += stride * 4) {
    float4 v = *(const float4*)(in + e);
    ushort4 u;
    u.x = f2bf_bits(v.x); u.y = f2bf_bits(v.y);
    u.z = f2bf_bits(v.z); u.w = f2bf_bits(v.w);
    *reinterpret_cast<ushort4*>(reinterpret_cast<unsigned short*>(out) + e) = u;
  }
}

// ---------------------------------------------------------------------------
// GEMM: C[M,N] = A[M,K] * B[N,K]^T   (both bf16, B^T layout)
// Tile (MF*32) x 256, BK=64, 8 waves, 512 threads; phase schedule with
// K-tile split into 2 half-tiles by k-slice; LDS double-buffered.
//   MF=8: 256x256 tile, waves 2Mx4N, per-wave 128x64 (QKV: grid 24x8)
//   MF=4: 128x256 tile, waves 2Mx4N, per-wave  64x64 (out-proj: grid 16x16,
//         full-machine occupancy — R14's 128-block grid idled half the CUs)
//  - tile t+1's loads spread across tile t's compute; counted vmcnt(L)
//    where L = loads/half-tile (MF=8: 4, MF=4: 3); vmcnt(0) only at the end
//  - s_setprio(1) around each MFMA cluster (T5)
//  - slot swizzle (slot ^= (row>>1)&3): linear LDS dest + inverse-permuted
//    global source (rule #21); measured 0 conflicts
//  - bijective XCD swizzle on flattened wgid (grids are %8 == 0)
// ---------------------------------------------------------------------------
template <bool OUT_BF16, int MF>
__global__ __launch_bounds__(512) void gemm_bt_kernel(
    const __hip_bfloat16* __restrict__ A, const __hip_bfloat16* __restrict__ B,
    void* __restrict__ Cv, int M, int N, int K) {
  extern __shared__ __hip_bfloat16 sAB[];
  constexpr int A_BUF = MF * 2048;       // elements of A per buffer
  constexpr int A_KS  = MF * 1024;       // elements per k-slice of A
  constexpr int BUFSZ = A_BUF + 16384;   // + B (256 rows x 32 el) x 2 slices
  const int tid = threadIdx.x;
  const int w = tid >> 6, l = tid & 63;
  const int wm = w >> 2, wn = w & 3;
  const int lr = l & 15;

  const int nbx = gridDim.x;
  const int nwg = nbx * gridDim.y;
  int wgid = blockIdx.y * nbx + blockIdx.x;
  wgid = (wgid & 7) * (nwg >> 3) + (wgid >> 3);  // XCD chunking
  const int brow = (wgid / nbx) * (MF * 32);
  const int bcol = (wgid % nbx) * 256;

  f32x4 acc[MF][4];
#pragma unroll
  for (int m = 0; m < MF; m++)
#pragma unroll
    for (int n = 0; n < 4; n++) acc[m][n] = (f32x4){0.f, 0.f, 0.f, 0.f};

  // staging: 512 threads cover 128 rows x 4 slots per issue (linear LDS dest);
  // source col8 permuted so LDS slot p holds global slot p ^ ((row>>1)&3)
  const int r0 = tid >> 2;                                  // 0..127
  const int c0s = (((tid & 3) ^ ((tid >> 3) & 3)) << 3);    // elements
  const __hip_bfloat16* Ag = A + (size_t)(brow + r0) * K + c0s;
  const __hip_bfloat16* Bg = B + (size_t)(bcol + r0) * K + c0s;
  const int ldst = tid * 8;

  // read: logical slot (l>>4) lives at slot (l>>4) ^ ((lr>>1)&3)
  const int sw8 = (((l >> 4) ^ ((lr >> 1) & 3)) << 3);

#define STG_A(BUF, K0, KS, RB)                                                \
  GLOAD_LDS16(Ag + (K0) + (KS) * 32 + (size_t)((RB) * 128) * K,               \
              sAB + (BUF) * BUFSZ + (KS) * A_KS + (RB) * 4096 + ldst)
#define STG_B(BUF, K0, KS, RB)                                                \
  GLOAD_LDS16(Bg + (K0) + (KS) * 32 + (size_t)((RB) * 128) * K,               \
              sAB + (BUF) * BUFSZ + A_BUF + (KS) * 8192 + (RB) * 4096 + ldst)
#define STG_A_ALL(BUF, K0, KS)                                                \
  {                                                                           \
    STG_A(BUF, K0, KS, 0);                                                    \
    if constexpr (MF == 8) STG_A(BUF, K0, KS, 1);                             \
  }

#define WAIT_L()                                                              \
  {                                                                           \
    if constexpr (MF == 8)                                                    \
      asm volatile("s_waitcnt vmcnt(4)" ::: "memory");                        \
    else                                                                      \
      asm volatile("s_waitcnt vmcnt(3)" ::: "memory");                        \
  }

// one n-pair cluster: reads bfr[2], MF*2 MFMAs into acc[.][NP*2+j]
#define CLUSTER(BB, NP)                                                       \
  {                                                                           \
    bf16x8 bfr[2];                                                            \
    _Pragma("unroll") for (int j = 0; j < 2; j++) bfr[j] =                    \
        *(const bf16x8*)&(BB)[(wn * 64 + ((NP)*2 + j) * 16 + lr) * 32 + sw8]; \
    __builtin_amdgcn_s_setprio(1);                                            \
    _Pragma("unroll") for (int mm = 0; mm < MF; mm++)                         \
        _Pragma("unroll") for (int j = 0; j < 2; j++)                         \
        acc[mm][(NP)*2 + j] = __builtin_amdgcn_mfma_f32_16x16x32_bf16(        \
            af[mm], bfr[j], acc[mm][(NP)*2 + j], 0, 0, 0);                    \
    __builtin_amdgcn_s_setprio(0);                                            \
  }

  const int nt = K >> 6;  // K-tiles of 64
  // prologue: stage tile 0 into buffer 0, half-tile order ks0 then ks1
  STG_A_ALL(0, 0, 0);
  STG_B(0, 0, 0, 0); STG_B(0, 0, 0, 1);
  STG_A_ALL(0, 0, 1);
  STG_B(0, 0, 1, 0); STG_B(0, 0, 1, 1);

  for (int t = 0; t < nt; ++t) {
    const int buf = t & 1, nb = buf ^ 1;
    const int k1 = (t + 1) << 6;
    const bool hn = (t + 1) < nt;
    const __hip_bfloat16* ab0 = sAB + buf * BUFSZ;
    const __hip_bfloat16* bb0 = ab0 + A_BUF;

    // ---- half-tile ks=0 ----  (its loads are the oldest outstanding)
    WAIT_L();
    __builtin_amdgcn_s_barrier();
    __builtin_amdgcn_sched_barrier(0);
    if (hn) STG_A_ALL(nb, k1, 0);
    {
      bf16x8 af[MF];
#pragma unroll
      for (int mm = 0; mm < MF; mm++)
        af[mm] = *(const bf16x8*)&ab0[(wm * MF * 16 + mm * 16 + lr) * 32 + sw8];
      CLUSTER(bb0, 0);
      if (hn) { STG_B(nb, k1, 0, 0); STG_B(nb, k1, 0, 1); }
      CLUSTER(bb0, 1);
    }
    // ---- half-tile ks=1 ----
    if (hn) {
      WAIT_L();
    } else {
      asm volatile("s_waitcnt vmcnt(0)" ::: "memory");
    }
    __builtin_amdgcn_s_barrier();
    __builtin_amdgcn_sched_barrier(0);
    if (hn) STG_A_ALL(nb, k1, 1);
    {
      const __hip_bfloat16* ab1 = ab0 + A_KS;
      const __hip_bfloat16* bb1 = bb0 + 8192;
      bf16x8 af[MF];
#pragma unroll
      for (int mm = 0; mm < MF; mm++)
        af[mm] = *(const bf16x8*)&ab1[(wm * MF * 16 + mm * 16 + lr) * 32 + sw8];
      CLUSTER(bb1, 0);
      if (hn) { STG_B(nb, k1, 1, 0); STG_B(nb, k1, 1, 1); }
      CLUSTER(bb1, 1);
    }
  }
#undef STG_A
#undef STG_B
#undef STG_A_ALL
#undef WAIT_L
#undef CLUSTER

  const int jr = (l >> 4) << 2;
  if (OUT_BF16) {
    __hip_bfloat16* C = (__hip_bfloat16*)Cv;
#pragma unroll
    for (int m = 0; m < MF; m++)
#pragma unroll
      for (int n = 0; n < 4; n++)
#pragma unroll
        for (int j = 0; j < 4; j++) {
          size_t row = brow + wm * MF * 16 + m * 16 + jr + j;
          size_t col = bcol + wn * 64 + n * 16 + lr;
          C[row * N + col] = __float2bfloat16(acc[m][n][j]);
        }
  } else {
    float* C = (float*)Cv;
#pragma unroll
    for (int m = 0; m < MF; m++)
#pragma unroll
      for (int n = 0; n < 4; n++)
#pragma unroll
        for (int j = 0; j < 4; j++) {
          size_t row = brow + wm * MF * 16 + m * 16 + jr + j;
          size_t col = bcol + wn * 64 + n * 16 + lr;
          C[row * N + col] = acc[m][n][j];
        }
  }
}

// ---------------------------------------------------------------------------
// RoPE (neox) in-place on Q (heads 0..31) and K (heads 32..39) of QKV.
// ---------------------------------------------------------------------------
__global__ void rope_kernel(__hip_bfloat16* __restrict__ QKV,
                            const int* __restrict__ pos) {
  int idx = blockIdx.x * blockDim.x + threadIdx.x;  // S*40*64 total
  int d = idx & 63;
  int head = (idx >> 6) % 40;
  int s = idx / (64 * 40);
  float p = (float)pos[s];
  float inv = exp2f(-(float)d * 0.2076205059304297f);
  float fr = p * inv;
  float sn, cs;
  sincosf(fr, &sn, &cs);
  size_t base = (size_t)s * QKV_LD + head * 128 + d;
  float x1 = __bfloat162float(QKV[base]);
  float x2 = __bfloat162float(QKV[base + 64]);
  QKV[base]      = __float2bfloat16(x1 * cs - x2 * sn);
  QKV[base + 64] = __float2bfloat16(x2 * cs + x1 * sn);
}

// ---------------------------------------------------------------------------
// Pack K and V into fragment-ordered buffers so attn loads are coalesced.
//   Kf element (kvh,t,ks,lane,j)       = K[kvh][t*32+(lane&31)][ks*16+(lane>>5)*8+j]
//   Vf element (kvh,t,slot=db*2+k2,lane,j) = V[kvh][t*32+k2*16+(lane>>5)*8+j][db*32+(lane&31)]
// 16B chunk id o: lane=o&63, slot=(o>>6)&7, t=(o>>9)&63, kvh=(o>>15)&7, K/V=o>>18.
// ---------------------------------------------------------------------------
__global__ void packkv_kernel(const __hip_bfloat16* __restrict__ QKV,
                              __hip_bfloat16* __restrict__ Kf,
                              __hip_bfloat16* __restrict__ Vf) {
  int o = blockIdx.x * blockDim.x + threadIdx.x;  // 2 * 2^18 chunks
  const int lane = o & 63;
  const int slot = (o >> 6) & 7;
  const int t    = (o >> 9) & 63;
  const int kvh  = (o >> 15) & 7;
  const int off8 = (o & 0x3FFFF) * 8;
  if (o < (1 << 18)) {
    // K: contiguous 8 along d
    const int s  = t * 32 + (lane & 31);
    const int d0 = slot * 16 + (lane >> 5) * 8;
    bf16x8 v = *(const bf16x8*)(QKV + (size_t)s * QKV_LD + 4096 + kvh * DH + d0);
    *(bf16x8*)(Kf + off8) = v;
  } else {
    // V: gather 8 along s at fixed d (transpose)
    const int s0 = t * 32 + (slot & 1) * 16 + (lane >> 5) * 8;
    const int d  = (slot >> 1) * 32 + (lane & 31);
    const __hip_bfloat16* src = QKV + (size_t)s0 * QKV_LD + 5120 + kvh * DH + d;
    ushort4 a, b;
    a.x = __builtin_bit_cast(unsigned short, src[0 * QKV_LD]);
    a.y = __builtin_bit_cast(unsigned short, src[1 * QKV_LD]);
    a.z = __builtin_bit_cast(unsigned short, src[2 * QKV_LD]);
    a.w = __builtin_bit_cast(unsigned short, src[3 * QKV_LD]);
    b.x = __builtin_bit_cast(unsigned short, src[4 * QKV_LD]);
    b.y = __builtin_bit_cast(unsigned short, src[5 * QKV_LD]);
    b.z = __builtin_bit_cast(unsigned short, src[6 * QKV_LD]);
    b.w = __builtin_bit_cast(unsigned short, src[7 * QKV_LD]);
    *(ushort4*)(Vf + off8)     = a;
    *(ushort4*)(Vf + off8 + 4) = b;
  }
}

// ---------------------------------------------------------------------------
// Causal GQA flash attention (unchanged from R11): swapped-QK 32x32 +
// split-KV x2, coalesced fragment-ordered K/V loads.
// ---------------------------------------------------------------------------
__global__ __launch_bounds__(256, 2) void attn_kernel(
    const __hip_bfloat16* __restrict__ QKV, const __hip_bfloat16* __restrict__ Kf,
    const __hip_bfloat16* __restrict__ Vf, __hip_bfloat16* __restrict__ O) {
  __shared__ float Ms[2][64][67];  // [head-slot][lane][64 oacc + m + lsum]
  const int tid = threadIdx.x;
  const int w = tid >> 6, l = tid & 63;
  const int l31 = l & 31;
  const int hiP = l >> 5;
  const int bid = blockIdx.x;
  const int kvh = bid & 7;                 // XCD-resident kv head
  const int hp = (bid >> 3) & 1;           // head pair within kv group
  const int qt = 63 - (bid >> 4);          // longest blocks dispatched first
  const int half = w >> 1;                 // kv-range half
  const int h = kvh * 4 + hp * 2 + (w & 1);
  const int qwb = qt * 32;                 // q base row
  const int qg = qwb + l31;                // this lane's q row

  const __hip_bfloat16* Qp  = QKV + (size_t)h * DH;
  const __hip_bfloat16* Kfp = Kf + (size_t)kvh * 262144 + l * 8;
  const __hip_bfloat16* Vfp = Vf + (size_t)kvh * 262144 + l * 8;

  // Q B-frags (held whole kernel): qf[ks] = Q[q=l31][ks*16 + hiP*8 .. +8]
  bf16x8 qf[8];
  {
    const __hip_bfloat16* qrow = Qp + (size_t)(qwb + l31) * QKV_LD + hiP * 8;
#pragma unroll
    for (int ks = 0; ks < 8; ks++) qf[ks] = *(const bf16x8*)(qrow + ks * 16);
  }

  f32x16 oacc[4];
#pragma unroll
  for (int db = 0; db < 4; db++)
#pragma unroll
    for (int r = 0; r < 16; r++) oacc[db][r] = 0.f;
  float m = -1e30f, lsum = 0.f;

#define COMPUTE_TILE(KB, MASKED)                                               \
  {                                                                            \
    const int kb_ = (KB);                                                      \
    const int toff_ = (kb_ >> 5) * 4096;                                       \
    f32x16 sacc;                                                               \
    _Pragma("unroll") for (int r = 0; r < 16; r++) sacc[r] = 0.f;              \
    {                                                                          \
      bf16x8 kf[8];                                                            \
      _Pragma("unroll") for (int ks = 0; ks < 8; ks++) kf[ks] =                \
          *(const bf16x8*)(Kfp + toff_ + ks * 512);                            \
      _Pragma("unroll") for (int ks = 0; ks < 8; ks++) sacc =                  \
          __builtin_amdgcn_mfma_f32_32x32x16_bf16(kf[ks], qf[ks], sacc, 0, 0,  \
                                                  0);                          \
    }                                                                          \
    bf16x8 vf[4][2];                                                           \
    _Pragma("unroll") for (int db = 0; db < 4; db++)                           \
        _Pragma("unroll") for (int k2 = 0; k2 < 2; k2++) vf[db][k2] =          \
        *(const bf16x8*)(Vfp + toff_ + (db * 2 + k2) * 512);                   \
    float s[16];                                                               \
    _Pragma("unroll") for (int r = 0; r < 16; r++) s[r] = sacc[r] * C2F;       \
    if (MASKED) {                                                              \
      _Pragma("unroll") for (int r = 0; r < 16; r++) {                         \
        const int kvg = kb_ + (r & 3) + 8 * (r >> 2) + 4 * hiP;                \
        s[r] = (kvg <= qg) ? s[r] : -1e30f;                                    \
      }                                                                        \
    }                                                                          \
    float m0 = fmaxf(fmaxf(s[0], s[1]), fmaxf(s[2], s[3]));                    \
    float m1 = fmaxf(fmaxf(s[4], s[5]), fmaxf(s[6], s[7]));                    \
    float m2 = fmaxf(fmaxf(s[8], s[9]), fmaxf(s[10], s[11]));                  \
    float m3 = fmaxf(fmaxf(s[12], s[13]), fmaxf(s[14], s[15]));                \
    float rmax = fmaxf(fmaxf(m0, m1), fmaxf(m2, m3));                          \
    rmax = fmaxf(rmax, xhalf(rmax, hiP));                                      \
    if (__any(rmax - m > 8.0f)) {                                              \
      float mn = fmaxf(m, rmax);                                               \
      float sc = __builtin_amdgcn_exp2f(m - mn);                               \
      lsum *= sc;                                                              \
      _Pragma("unroll") for (int db = 0; db < 4; db++)                         \
          _Pragma("unroll") for (int r = 0; r < 16; r++) oacc[db][r] *= sc;    \
      m = mn;                                                                  \
    }                                                                          \
    float p[16];                                                               \
    _Pragma("unroll") for (int r = 0; r < 16; r++) p[r] =                      \
        __builtin_amdgcn_exp2f(s[r] - m);                                      \
    float rs = ((p[0] + p[1]) + (p[2] + p[3])) +                               \
               ((p[4] + p[5]) + (p[6] + p[7])) +                               \
               ((p[8] + p[9]) + (p[10] + p[11])) +                             \
               ((p[12] + p[13]) + (p[14] + p[15]));                            \
    lsum += rs + xhalf(rs, hiP);                                               \
    unsigned Wp[8];                                                            \
    _Pragma("unroll") for (int i = 0; i < 8; i++) Wp[i] =                      \
        (unsigned)f2bf_bits(p[2 * i]) |                                        \
        ((unsigned)f2bf_bits(p[2 * i + 1]) << 16);                             \
    unsigned s0x = Wp[0], s0y = Wp[2];                                         \
    unsigned s1x = Wp[1], s1y = Wp[3];                                         \
    unsigned s2x = Wp[4], s2y = Wp[6];                                         \
    unsigned s3x = Wp[5], s3y = Wp[7];                                         \
    plswap(s0x, s0y);                                                          \
    plswap(s1x, s1y);                                                          \
    plswap(s2x, s2y);                                                          \
    plswap(s3x, s3y);                                                          \
    int4 f0, f1;                                                               \
    f0.x = (int)s0x; f0.y = (int)s1x; f0.z = (int)s0y; f0.w = (int)s1y;        \
    f1.x = (int)s2x; f1.y = (int)s3x; f1.z = (int)s2y; f1.w = (int)s3y;        \
    bf16x8 pfrag[2];                                                           \
    pfrag[0] = __builtin_bit_cast(bf16x8, f0);                                 \
    pfrag[1] = __builtin_bit_cast(bf16x8, f1);                                 \
    _Pragma("unroll") for (int db = 0; db < 4; db++)                           \
        _Pragma("unroll") for (int k2 = 0; k2 < 2; k2++) oacc[db] =            \
        __builtin_amdgcn_mfma_f32_32x32x16_bf16(vf[db][k2], pfrag[k2],         \
                                                oacc[db], 0, 0, 0);            \
  }

  const int nt = qt + 1;
  const int nt0 = nt >> 1;  // tiles in half 0 (may be 0)

  if (half) {
    for (int kb = nt0 * 32; kb < qwb; kb += 32) COMPUTE_TILE(kb, false);
    COMPUTE_TILE(qwb, true);
  } else {
    const int kend = nt0 * 32;
    for (int kb = 0; kb < kend; kb += 32) COMPUTE_TILE(kb, false);
  }
#undef COMPUTE_TILE

  // ---- split-KV merge ----
  if (half) {
    float* dst = Ms[w & 1][l];
#pragma unroll
    for (int db = 0; db < 4; db++)
#pragma unroll
      for (int r = 0; r < 16; r++) dst[db * 16 + r] = oacc[db][r];
    dst[64] = m;
    dst[65] = lsum;
  }
  __syncthreads();
  if (!half) {
    const float* src = Ms[w & 1][l];
    const float mB = src[64], lB = src[65];
    const float mS = fmaxf(m, mB);
    float fa = __builtin_amdgcn_exp2f(m - mS);
    float fb = __builtin_amdgcn_exp2f(mB - mS);
    const float inv = 1.0f / (lsum * fa + lB * fb);
    fa *= inv;
    fb *= inv;
    // write O[q][h*128 + d], d = db*32 + 8*rg + 4*hiP + (r&3)
    __hip_bfloat16* orow = O + (size_t)qg * (NQH * DH) + h * DH;
#pragma unroll
    for (int db = 0; db < 4; db++)
#pragma unroll
      for (int rg = 0; rg < 4; rg++) {
        ushort4 u;
        u.x = f2bf_bits(oacc[db][rg * 4 + 0] * fa + src[db * 16 + rg * 4 + 0] * fb);
        u.y = f2bf_bits(oacc[db][rg * 4 + 1] * fa + src[db * 16 + rg * 4 + 1] * fb);
        u.z = f2bf_bits(oacc[db][rg * 4 + 2] * fa + src[db * 16 + rg * 4 + 2] * fb);
        u.w = f2bf_bits(oacc[db][rg * 4 + 3] * fa + src[db * 16 + rg * 4 + 3] * fb);
        *reinterpret_cast<ushort4*>(orow + db * 32 + 8 * rg + 4 * hiP) = u;
      }
  }
}

// ---------------------------------------------------------------------------
extern "C" void kernel_launch(void* const* d_in, const int* in_sizes, int n_in,
                              void* d_out, int out_size, void* d_ws,
                              size_t ws_size, hipStream_t stream) {
  const float* hs = (const float*)d_in[0];
  const int* pos = (const int*)d_in[1];
  const float* wqkv = (const float*)d_in[2];
  const float* wo = (const float*)d_in[3];
  float* out = (float*)d_out;

  char* ws = (char*)d_ws;
  __hip_bfloat16* Xb      = (__hip_bfloat16*)(ws);                // 16 MB
  __hip_bfloat16* Wqkvb   = (__hip_bfloat16*)(ws + 16777216);     // 48 MB
  __hip_bfloat16* Wob     = (__hip_bfloat16*)(ws + 67108864);     // 32 MB
  __hip_bfloat16* QKV     = (__hip_bfloat16*)(ws + 100663296);    // 24 MB
  __hip_bfloat16* AttnOut = (__hip_bfloat16*)(ws + 125829120);    // 16 MB
  __hip_bfloat16* Kf      = (__hip_bfloat16*)(ws + 142606336);    // 4 MB
  __hip_bfloat16* Vf      = (__hip_bfloat16*)(ws);                // 4 MB (Xb dead after gemm1)

  cvt_f32_bf16<<<2048, 256, 0, stream>>>(hs, Xb, S_SEQ * HID);
  cvt_f32_bf16<<<2048, 256, 0, stream>>>(wqkv, Wqkvb, QKV_LD * HID);
  cvt_f32_bf16<<<2048, 256, 0, stream>>>(wo, Wob, HID * HID);

  gemm_bt_kernel<true, 8>
      <<<dim3(QKV_LD / 256, S_SEQ / 256), 512, 131072, stream>>>(
          Xb, Wqkvb, QKV, S_SEQ, QKV_LD, HID);

  rope_kernel<<<(S_SEQ * 40 * 64) / 256, 256, 0, stream>>>(QKV, pos);
  packkv_kernel<<<2048, 256, 0, stream>>>(QKV, Kf, Vf);

  attn_kernel<<<1024, 256, 0, stream>>>(QKV, Kf, Vf, AttnOut);

  gemm_bt_kernel<false, 4>
      <<<dim3(HID / 256, S_SEQ / 128), 512, 98304, stream>>>(
          AttnOut, Wob, out, S_SEQ, HID, HID);
}

// Round 16
// 305.387 us; speedup vs baseline: 1.1179x; 1.0259x over previous
//
#include <hip/hip_runtime.h>
#include <hip/hip_bf16.h>
#include <cstdint>

#define S_SEQ   2048
#define HID     4096
#define NQH     32
#define NKVH    8
#define DH      128
#define QKV_LD  6144      // (32+16)*128
#define SCALE_F 0.08838834764831845f
// softmax in log2 domain: s' = s * SCALE * log2(e)
#define C2F (0.08838834764831845f * 1.4426950408889634f)

using f32x4  = __attribute__((ext_vector_type(4))) float;
using f32x16 = __attribute__((ext_vector_type(16))) float;
using bf16x8 = __attribute__((ext_vector_type(8))) __bf16;
using u32x2  = __attribute__((ext_vector_type(2))) unsigned;

#define GLOAD_LDS16(gp, lp)                                                   \
  __builtin_amdgcn_global_load_lds(                                           \
      (__attribute__((address_space(1))) const void*)(gp),                    \
      (__attribute__((address_space(3))) void*)(lp), 16, 0, 0)

__device__ __forceinline__ unsigned short f2bf_bits(float f) {
  __hip_bfloat16 b = __float2bfloat16(f);
  return __builtin_bit_cast(unsigned short, b);
}

// permlane32_swap: X[32..63] <-> Y[0..31].
__device__ __forceinline__ void plswap(unsigned& x, unsigned& y) {
  u32x2 r = __builtin_amdgcn_permlane32_swap(x, y, false, false);
  x = r[0];
  y = r[1];
}
// value of the partner lane (l ^ 32)
__device__ __forceinline__ float xhalf(float v, int hiP) {
  unsigned u = __builtin_bit_cast(unsigned, v);
  u32x2 r = __builtin_amdgcn_permlane32_swap(u, u, false, false);
  return __builtin_bit_cast(float, hiP ? r[0] : r[1]);
}

// ---------------------------------------------------------------------------
// merged f32 -> bf16 conversion for hs + wqkv (single kernel, fewer tails)
// ---------------------------------------------------------------------------
__global__ void cvt2_kernel(const float* __restrict__ hs,
                            __hip_bfloat16* __restrict__ hsb,
                            const float* __restrict__ wq,
                            __hip_bfloat16* __restrict__ wqb) {
  const int NHS = (S_SEQ * HID) / 4;     // 2,097,152 float4
  const int NWQ = (QKV_LD * HID) / 4;    // 6,291,456 float4
  int i = blockIdx.x * blockDim.x + threadIdx.x;
  int stride = gridDim.x * blockDim.x;
  for (int e = i; e < NHS + NWQ; e += stride) {
    const float4* src;
    ushort4* dst;
    int idx;
    if (e < NHS) {
      src = (const float4*)hs; dst = (ushort4*)hsb; idx = e;
    } else {
      src = (const float4*)wq; dst = (ushort4*)wqb; idx = e - NHS;
    }
    float4 v = src[idx];
    ushort4 u;
    u.x = f2bf_bits(v.x); u.y = f2bf_bits(v.y);
    u.z = f2bf_bits(v.z); u.w = f2bf_bits(v.w);
    dst[idx] = u;
  }
}

// ---------------------------------------------------------------------------
// GEMM: C[M,N] = A[M,K] * B[N,K]^T   (both bf16, B^T layout)
// Tile (MF*32) x 256, BK=64, 8 waves, 512 threads; phase schedule with
// K-tile split into 2 half-tiles; LDS double-buffered; counted vmcnt.
//   MF=8: 256x256 (QKV, grid 32x8: blocks x<24 = GEMM, x>=24 = fused wo-cvt
//          riding the otherwise-idle 64 CUs)
//   MF=4: 128x256 (out-proj, grid 16x16, full occupancy)
//  - column-major wgid decode: each XCD's contiguous chunk shares B panels
//    (4-6 MB, L2-resident) instead of streaming all of B per XCD
//  - slot swizzle (slot ^= (row>>1)&3) linear-dest + inverse-permuted source
//  - bijective XCD swizzle on flattened wgid (grids are %8 == 0)
// ---------------------------------------------------------------------------
template <bool OUT_BF16, int MF, bool FUSE>
__global__ __launch_bounds__(512) void gemm_bt_kernel(
    const __hip_bfloat16* __restrict__ A, const __hip_bfloat16* __restrict__ B,
    void* __restrict__ Cv, int M, int N, int K, int nbx_main,
    const float* __restrict__ csrc, __hip_bfloat16* __restrict__ cdst,
    int cn4) {
  extern __shared__ __hip_bfloat16 sAB[];
  constexpr int A_BUF = MF * 2048;       // elements of A per buffer
  constexpr int A_KS  = MF * 1024;       // elements per k-slice of A
  constexpr int BUFSZ = A_BUF + 16384;   // + B (256 rows x 32 el) x 2 slices
  const int tid = threadIdx.x;

  if (FUSE) {
    if ((int)blockIdx.x >= nbx_main) {
      // fused f32->bf16 conversion on blocks the GEMM grid can't fill
      const int nb = gridDim.x - nbx_main;
      const int cid = ((int)blockIdx.x - nbx_main) + (int)blockIdx.y * nb;
      const int stride = nb * gridDim.y * 512;
      for (int e = cid * 512 + tid; e < cn4; e += stride) {
        float4 v = ((const float4*)csrc)[e];
        ushort4 u;
        u.x = f2bf_bits(v.x); u.y = f2bf_bits(v.y);
        u.z = f2bf_bits(v.z); u.w = f2bf_bits(v.w);
        ((ushort4*)cdst)[e] = u;
      }
      return;
    }
  }

  const int w = tid >> 6, l = tid & 63;
  const int wm = w >> 2, wn = w & 3;
  const int lr = l & 15;

  const int nbx = nbx_main;
  const int gdy = gridDim.y;
  const int nwg = nbx * gdy;
  int wgid = blockIdx.y * nbx + blockIdx.x;
  wgid = (wgid & 7) * (nwg >> 3) + (wgid >> 3);  // XCD chunking
  // column-major decode: consecutive wgid share B panels within an XCD
  const int bx = wgid / gdy;
  const int by = wgid % gdy;
  const int brow = by * (MF * 32);
  const int bcol = bx * 256;

  f32x4 acc[MF][4];
#pragma unroll
  for (int m = 0; m < MF; m++)
#pragma unroll
    for (int n = 0; n < 4; n++) acc[m][n] = (f32x4){0.f, 0.f, 0.f, 0.f};

  const int r0 = tid >> 2;                                  // 0..127
  const int c0s = (((tid & 3) ^ ((tid >> 3) & 3)) << 3);    // elements
  const __hip_bfloat16* Ag = A + (size_t)(brow + r0) * K + c0s;
  const __hip_bfloat16* Bg = B + (size_t)(bcol + r0) * K + c0s;
  const int ldst = tid * 8;

  const int sw8 = (((l >> 4) ^ ((lr >> 1) & 3)) << 3);

#define STG_A(BUF, K0, KS, RB)                                                \
  GLOAD_LDS16(Ag + (K0) + (KS) * 32 + (size_t)((RB) * 128) * K,               \
              sAB + (BUF) * BUFSZ + (KS) * A_KS + (RB) * 4096 + ldst)
#define STG_B(BUF, K0, KS, RB)                                                \
  GLOAD_LDS16(Bg + (K0) + (KS) * 32 + (size_t)((RB) * 128) * K,               \
              sAB + (BUF) * BUFSZ + A_BUF + (KS) * 8192 + (RB) * 4096 + ldst)
#define STG_A_ALL(BUF, K0, KS)                                                \
  {                                                                           \
    STG_A(BUF, K0, KS, 0);                                                    \
    if constexpr (MF == 8) STG_A(BUF, K0, KS, 1);                             \
  }

#define WAIT_L()                                                              \
  {                                                                           \
    if constexpr (MF == 8)                                                    \
      asm volatile("s_waitcnt vmcnt(4)" ::: "memory");                        \
    else                                                                      \
      asm volatile("s_waitcnt vmcnt(3)" ::: "memory");                        \
  }

#define CLUSTER(BB, NP)                                                       \
  {                                                                           \
    bf16x8 bfr[2];                                                            \
    _Pragma("unroll") for (int j = 0; j < 2; j++) bfr[j] =                    \
        *(const bf16x8*)&(BB)[(wn * 64 + ((NP)*2 + j) * 16 + lr) * 32 + sw8]; \
    __builtin_amdgcn_s_setprio(1);                                            \
    _Pragma("unroll") for (int mm = 0; mm < MF; mm++)                         \
        _Pragma("unroll") for (int j = 0; j < 2; j++)                         \
        acc[mm][(NP)*2 + j] = __builtin_amdgcn_mfma_f32_16x16x32_bf16(        \
            af[mm], bfr[j], acc[mm][(NP)*2 + j], 0, 0, 0);                    \
    __builtin_amdgcn_s_setprio(0);                                            \
  }

  const int nt = K >> 6;  // K-tiles of 64
  STG_A_ALL(0, 0, 0);
  STG_B(0, 0, 0, 0); STG_B(0, 0, 0, 1);
  STG_A_ALL(0, 0, 1);
  STG_B(0, 0, 1, 0); STG_B(0, 0, 1, 1);

  for (int t = 0; t < nt; ++t) {
    const int buf = t & 1, nb2 = buf ^ 1;
    const int k1 = (t + 1) << 6;
    const bool hn = (t + 1) < nt;
    const __hip_bfloat16* ab0 = sAB + buf * BUFSZ;
    const __hip_bfloat16* bb0 = ab0 + A_BUF;

    // ---- half-tile ks=0 ----
    WAIT_L();
    __builtin_amdgcn_s_barrier();
    __builtin_amdgcn_sched_barrier(0);
    if (hn) STG_A_ALL(nb2, k1, 0);
    {
      bf16x8 af[MF];
#pragma unroll
      for (int mm = 0; mm < MF; mm++)
        af[mm] = *(const bf16x8*)&ab0[(wm * MF * 16 + mm * 16 + lr) * 32 + sw8];
      CLUSTER(bb0, 0);
      if (hn) { STG_B(nb2, k1, 0, 0); STG_B(nb2, k1, 0, 1); }
      CLUSTER(bb0, 1);
    }
    // ---- half-tile ks=1 ----
    if (hn) {
      WAIT_L();
    } else {
      asm volatile("s_waitcnt vmcnt(0)" ::: "memory");
    }
    __builtin_amdgcn_s_barrier();
    __builtin_amdgcn_sched_barrier(0);
    if (hn) STG_A_ALL(nb2, k1, 1);
    {
      const __hip_bfloat16* ab1 = ab0 + A_KS;
      const __hip_bfloat16* bb1 = bb0 + 8192;
      bf16x8 af[MF];
#pragma unroll
      for (int mm = 0; mm < MF; mm++)
        af[mm] = *(const bf16x8*)&ab1[(wm * MF * 16 + mm * 16 + lr) * 32 + sw8];
      CLUSTER(bb1, 0);
      if (hn) { STG_B(nb2, k1, 1, 0); STG_B(nb2, k1, 1, 1); }
      CLUSTER(bb1, 1);
    }
  }
#undef STG_A
#undef STG_B
#undef STG_A_ALL
#undef WAIT_L
#undef CLUSTER

  const int jr = (l >> 4) << 2;
  if (OUT_BF16) {
    __hip_bfloat16* C = (__hip_bfloat16*)Cv;
#pragma unroll
    for (int m = 0; m < MF; m++)
#pragma unroll
      for (int n = 0; n < 4; n++)
#pragma unroll
        for (int j = 0; j < 4; j++) {
          size_t row = brow + wm * MF * 16 + m * 16 + jr + j;
          size_t col = bcol + wn * 64 + n * 16 + lr;
          C[row * N + col] = __float2bfloat16(acc[m][n][j]);
        }
  } else {
    float* C = (float*)Cv;
#pragma unroll
    for (int m = 0; m < MF; m++)
#pragma unroll
      for (int n = 0; n < 4; n++)
#pragma unroll
        for (int j = 0; j < 4; j++) {
          size_t row = brow + wm * MF * 16 + m * 16 + jr + j;
          size_t col = bcol + wn * 64 + n * 16 + lr;
          C[row * N + col] = acc[m][n][j];
        }
  }
}

// ---------------------------------------------------------------------------
// RoPE (neox) in-place on Q only (heads 0..31); K rope is fused into packkv.
// ---------------------------------------------------------------------------
__global__ void ropeq_kernel(__hip_bfloat16* __restrict__ QKV,
                             const int* __restrict__ pos) {
  int idx = blockIdx.x * blockDim.x + threadIdx.x;  // S*32*64 total
  int d = idx & 63;
  int head = (idx >> 6) & 31;
  int s = idx >> 11;
  float p = (float)pos[s];
  float inv = exp2f(-(float)d * 0.2076205059304297f);
  float fr = p * inv;
  float sn, cs;
  sincosf(fr, &sn, &cs);
  size_t base = (size_t)s * QKV_LD + head * 128 + d;
  float x1 = __bfloat162float(QKV[base]);
  float x2 = __bfloat162float(QKV[base + 64]);
  QKV[base]      = __float2bfloat16(x1 * cs - x2 * sn);
  QKV[base + 64] = __float2bfloat16(x2 * cs + x1 * sn);
}

// ---------------------------------------------------------------------------
// Pack K and V into fragment-ordered buffers (coalesced attn loads), with
// RoPE applied to K in-register during the pack (reads RAW K from QKV).
//   Kf element (kvh,t,ks,lane,j)       = rope(K)[kvh][t*32+(lane&31)][ks*16+(lane>>5)*8+j]
//   Vf element (kvh,t,slot=db*2+k2,lane,j) = V[kvh][t*32+k2*16+(lane>>5)*8+j][db*32+(lane&31)]
// ---------------------------------------------------------------------------
__global__ void packkv_kernel(const __hip_bfloat16* __restrict__ QKV,
                              const int* __restrict__ pos,
                              __hip_bfloat16* __restrict__ Kf,
                              __hip_bfloat16* __restrict__ Vf) {
  int o = blockIdx.x * blockDim.x + threadIdx.x;  // 2 * 2^18 chunks
  const int lane = o & 63;
  const int slot = (o >> 6) & 7;
  const int t    = (o >> 9) & 63;
  const int kvh  = (o >> 15) & 7;
  const int off8 = (o & 0x3FFFF) * 8;
  if (o < (1 << 18)) {
    // K with rope: own chunk at d0, partner at d0^64, freq idx (d0&63)+j
    const int s  = t * 32 + (lane & 31);
    const int d0 = slot * 16 + (lane >> 5) * 8;
    const __hip_bfloat16* kb = QKV + (size_t)s * QKV_LD + 4096 + kvh * DH;
    bf16x8 own = *(const bf16x8*)(kb + d0);
    bf16x8 prt = *(const bf16x8*)(kb + (d0 ^ 64));
    float p = (float)pos[s];
    bf16x8 outv;
#pragma unroll
    for (int j = 0; j < 8; j++) {
      float f = (float)((d0 & 63) + j);
      float inv = exp2f(-f * 0.2076205059304297f);
      float sn, cs;
      sincosf(p * inv, &sn, &cs);
      float a = (float)own[j], b = (float)prt[j];
      outv[j] = (__bf16)((d0 < 64) ? (a * cs - b * sn) : (a * cs + b * sn));
    }
    *(bf16x8*)(Kf + off8) = outv;
  } else {
    // V: gather 8 along s at fixed d (transpose)
    const int s0 = t * 32 + (slot & 1) * 16 + (lane >> 5) * 8;
    const int d  = (slot >> 1) * 32 + (lane & 31);
    const __hip_bfloat16* src = QKV + (size_t)s0 * QKV_LD + 5120 + kvh * DH + d;
    ushort4 a, b;
    a.x = __builtin_bit_cast(unsigned short, src[0 * QKV_LD]);
    a.y = __builtin_bit_cast(unsigned short, src[1 * QKV_LD]);
    a.z = __builtin_bit_cast(unsigned short, src[2 * QKV_LD]);
    a.w = __builtin_bit_cast(unsigned short, src[3 * QKV_LD]);
    b.x = __builtin_bit_cast(unsigned short, src[4 * QKV_LD]);
    b.y = __builtin_bit_cast(unsigned short, src[5 * QKV_LD]);
    b.z = __builtin_bit_cast(unsigned short, src[6 * QKV_LD]);
    b.w = __builtin_bit_cast(unsigned short, src[7 * QKV_LD]);
    *(ushort4*)(Vf + off8)     = a;
    *(ushort4*)(Vf + off8 + 4) = b;
  }
}

// ---------------------------------------------------------------------------
// Causal GQA flash attention (unchanged from R11): swapped-QK 32x32 +
// split-KV x2, coalesced fragment-ordered K/V loads.
// ---------------------------------------------------------------------------
__global__ __launch_bounds__(256, 2) void attn_kernel(
    const __hip_bfloat16* __restrict__ QKV, const __hip_bfloat16* __restrict__ Kf,
    const __hip_bfloat16* __restrict__ Vf, __hip_bfloat16* __restrict__ O) {
  __shared__ float Ms[2][64][67];  // [head-slot][lane][64 oacc + m + lsum]
  const int tid = threadIdx.x;
  const int w = tid >> 6, l = tid & 63;
  const int l31 = l & 31;
  const int hiP = l >> 5;
  const int bid = blockIdx.x;
  const int kvh = bid & 7;                 // XCD-resident kv head
  const int hp = (bid >> 3) & 1;           // head pair within kv group
  const int qt = 63 - (bid >> 4);          // longest blocks dispatched first
  const int half = w >> 1;                 // kv-range half
  const int h = kvh * 4 + hp * 2 + (w & 1);
  const int qwb = qt * 32;                 // q base row
  const int qg = qwb + l31;                // this lane's q row

  const __hip_bfloat16* Qp  = QKV + (size_t)h * DH;
  const __hip_bfloat16* Kfp = Kf + (size_t)kvh * 262144 + l * 8;
  const __hip_bfloat16* Vfp = Vf + (size_t)kvh * 262144 + l * 8;

  // Q B-frags (held whole kernel): qf[ks] = Q[q=l31][ks*16 + hiP*8 .. +8]
  bf16x8 qf[8];
  {
    const __hip_bfloat16* qrow = Qp + (size_t)(qwb + l31) * QKV_LD + hiP * 8;
#pragma unroll
    for (int ks = 0; ks < 8; ks++) qf[ks] = *(const bf16x8*)(qrow + ks * 16);
  }

  f32x16 oacc[4];
#pragma unroll
  for (int db = 0; db < 4; db++)
#pragma unroll
    for (int r = 0; r < 16; r++) oacc[db][r] = 0.f;
  float m = -1e30f, lsum = 0.f;

#define COMPUTE_TILE(KB, MASKED)                                               \
  {                                                                            \
    const int kb_ = (KB);                                                      \
    const int toff_ = (kb_ >> 5) * 4096;                                       \
    f32x16 sacc;                                                               \
    _Pragma("unroll") for (int r = 0; r < 16; r++) sacc[r] = 0.f;              \
    {                                                                          \
      bf16x8 kf[8];                                                            \
      _Pragma("unroll") for (int ks = 0; ks < 8; ks++) kf[ks] =                \
          *(const bf16x8*)(Kfp + toff_ + ks * 512);                            \
      _Pragma("unroll") for (int ks = 0; ks < 8; ks++) sacc =                  \
          __builtin_amdgcn_mfma_f32_32x32x16_bf16(kf[ks], qf[ks], sacc, 0, 0,  \
                                                  0);                          \
    }                                                                          \
    bf16x8 vf[4][2];                                                           \
    _Pragma("unroll") for (int db = 0; db < 4; db++)                           \
        _Pragma("unroll") for (int k2 = 0; k2 < 2; k2++) vf[db][k2] =          \
        *(const bf16x8*)(Vfp + toff_ + (db * 2 + k2) * 512);                   \
    float s[16];                                                               \
    _Pragma("unroll") for (int r = 0; r < 16; r++) s[r] = sacc[r] * C2F;       \
    if (MASKED) {                                                              \
      _Pragma("unroll") for (int r = 0; r < 16; r++) {                         \
        const int kvg = kb_ + (r & 3) + 8 * (r >> 2) + 4 * hiP;                \
        s[r] = (kvg <= qg) ? s[r] : -1e30f;                                    \
      }                                                                        \
    }                                                                          \
    float m0 = fmaxf(fmaxf(s[0], s[1]), fmaxf(s[2], s[3]));                    \
    float m1 = fmaxf(fmaxf(s[4], s[5]), fmaxf(s[6], s[7]));                    \
    float m2 = fmaxf(fmaxf(s[8], s[9]), fmaxf(s[10], s[11]));                  \
    float m3 = fmaxf(fmaxf(s[12], s[13]), fmaxf(s[14], s[15]));                \
    float rmax = fmaxf(fmaxf(m0, m1), fmaxf(m2, m3));                          \
    rmax = fmaxf(rmax, xhalf(rmax, hiP));                                      \
    if (__any(rmax - m > 8.0f)) {                                              \
      float mn = fmaxf(m, rmax);                                               \
      float sc = __builtin_amdgcn_exp2f(m - mn);                               \
      lsum *= sc;                                                              \
      _Pragma("unroll") for (int db = 0; db < 4; db++)                         \
          _Pragma("unroll") for (int r = 0; r < 16; r++) oacc[db][r] *= sc;    \
      m = mn;                                                                  \
    }                                                                          \
    float p[16];                                                               \
    _Pragma("unroll") for (int r = 0; r < 16; r++) p[r] =                      \
        __builtin_amdgcn_exp2f(s[r] - m);                                      \
    float rs = ((p[0] + p[1]) + (p[2] + p[3])) +                               \
               ((p[4] + p[5]) + (p[6] + p[7])) +                               \
               ((p[8] + p[9]) + (p[10] + p[11])) +                             \
               ((p[12] + p[13]) + (p[14] + p[15]));                            \
    lsum += rs + xhalf(rs, hiP);                                               \
    unsigned Wp[8];                                                            \
    _Pragma("unroll") for (int i = 0; i < 8; i++) Wp[i] =                      \
        (unsigned)f2bf_bits(p[2 * i]) |                                        \
        ((unsigned)f2bf_bits(p[2 * i + 1]) << 16);                             \
    unsigned s0x = Wp[0], s0y = Wp[2];                                         \
    unsigned s1x = Wp[1], s1y = Wp[3];                                         \
    unsigned s2x = Wp[4], s2y = Wp[6];                                         \
    unsigned s3x = Wp[5], s3y = Wp[7];                                         \
    plswap(s0x, s0y);                                                          \
    plswap(s1x, s1y);                                                          \
    plswap(s2x, s2y);                                                          \
    plswap(s3x, s3y);                                                          \
    int4 f0, f1;                                                               \
    f0.x = (int)s0x; f0.y = (int)s1x; f0.z = (int)s0y; f0.w = (int)s1y;        \
    f1.x = (int)s2x; f1.y = (int)s3x; f1.z = (int)s2y; f1.w = (int)s3y;        \
    bf16x8 pfrag[2];                                                           \
    pfrag[0] = __builtin_bit_cast(bf16x8, f0);                                 \
    pfrag[1] = __builtin_bit_cast(bf16x8, f1);                                 \
    _Pragma("unroll") for (int db = 0; db < 4; db++)                           \
        _Pragma("unroll") for (int k2 = 0; k2 < 2; k2++) oacc[db] =            \
        __builtin_amdgcn_mfma_f32_32x32x16_bf16(vf[db][k2], pfrag[k2],         \
                                                oacc[db], 0, 0, 0);            \
  }

  const int nt = qt + 1;
  const int nt0 = nt >> 1;  // tiles in half 0 (may be 0)

  if (half) {
    for (int kb = nt0 * 32; kb < qwb; kb += 32) COMPUTE_TILE(kb, false);
    COMPUTE_TILE(qwb, true);
  } else {
    const int kend = nt0 * 32;
    for (int kb = 0; kb < kend; kb += 32) COMPUTE_TILE(kb, false);
  }
#undef COMPUTE_TILE

  // ---- split-KV merge ----
  if (half) {
    float* dst = Ms[w & 1][l];
#pragma unroll
    for (int db = 0; db < 4; db++)
#pragma unroll
      for (int r = 0; r < 16; r++) dst[db * 16 + r] = oacc[db][r];
    dst[64] = m;
    dst[65] = lsum;
  }
  __syncthreads();
  if (!half) {
    const float* src = Ms[w & 1][l];
    const float mB = src[64], lB = src[65];
    const float mS = fmaxf(m, mB);
    float fa = __builtin_amdgcn_exp2f(m - mS);
    float fb = __builtin_amdgcn_exp2f(mB - mS);
    const float inv = 1.0f / (lsum * fa + lB * fb);
    fa *= inv;
    fb *= inv;
    // write O[q][h*128 + d], d = db*32 + 8*rg + 4*hiP + (r&3)
    __hip_bfloat16* orow = O + (size_t)qg * (NQH * DH) + h * DH;
#pragma unroll
    for (int db = 0; db < 4; db++)
#pragma unroll
      for (int rg = 0; rg < 4; rg++) {
        ushort4 u;
        u.x = f2bf_bits(oacc[db][rg * 4 + 0] * fa + src[db * 16 + rg * 4 + 0] * fb);
        u.y = f2bf_bits(oacc[db][rg * 4 + 1] * fa + src[db * 16 + rg * 4 + 1] * fb);
        u.z = f2bf_bits(oacc[db][rg * 4 + 2] * fa + src[db * 16 + rg * 4 + 2] * fb);
        u.w = f2bf_bits(oacc[db][rg * 4 + 3] * fa + src[db * 16 + rg * 4 + 3] * fb);
        *reinterpret_cast<ushort4*>(orow + db * 32 + 8 * rg + 4 * hiP) = u;
      }
  }
}

// ---------------------------------------------------------------------------
extern "C" void kernel_launch(void* const* d_in, const int* in_sizes, int n_in,
                              void* d_out, int out_size, void* d_ws,
                              size_t ws_size, hipStream_t stream) {
  const float* hs = (const float*)d_in[0];
  const int* pos = (const int*)d_in[1];
  const float* wqkv = (const float*)d_in[2];
  const float* wo = (const float*)d_in[3];
  float* out = (float*)d_out;

  char* ws = (char*)d_ws;
  __hip_bfloat16* Xb      = (__hip_bfloat16*)(ws);                // 16 MB
  __hip_bfloat16* Wqkvb   = (__hip_bfloat16*)(ws + 16777216);     // 48 MB
  __hip_bfloat16* Wob     = (__hip_bfloat16*)(ws + 67108864);     // 32 MB
  __hip_bfloat16* QKV     = (__hip_bfloat16*)(ws + 100663296);    // 24 MB
  __hip_bfloat16* AttnOut = (__hip_bfloat16*)(ws + 125829120);    // 16 MB
  __hip_bfloat16* Kf      = (__hip_bfloat16*)(ws + 142606336);    // 4 MB
  __hip_bfloat16* Vf      = (__hip_bfloat16*)(ws);                // 4 MB (Xb dead after gemm1)

  // hs + wqkv f32->bf16 (merged)
  cvt2_kernel<<<2048, 256, 0, stream>>>(hs, Xb, wqkv, Wqkvb);

  // QKV GEMM (blocks x<24) + wo f32->bf16 on the 64 otherwise-idle CUs
  gemm_bt_kernel<true, 8, true>
      <<<dim3(32, 8), 512, 131072, stream>>>(
          Xb, Wqkvb, QKV, S_SEQ, QKV_LD, HID, 24, wo, Wob, (HID * HID) / 4);

  ropeq_kernel<<<(S_SEQ * 32 * 64) / 256, 256, 0, stream>>>(QKV, pos);
  packkv_kernel<<<2048, 256, 0, stream>>>(QKV, pos, Kf, Vf);

  attn_kernel<<<1024, 256, 0, stream>>>(QKV, Kf, Vf, AttnOut);

  gemm_bt_kernel<false, 4, false>
      <<<dim3(16, 16), 512, 98304, stream>>>(
          AttnOut, Wob, out, S_SEQ, HID, HID, 16, nullptr, nullptr, 0);
}

// Round 17
// 303.338 us; speedup vs baseline: 1.1254x; 1.0068x over previous
//
#include <hip/hip_runtime.h>
#include <hip/hip_bf16.h>
#include <cstdint>

#define S_SEQ   2048
#define HID     4096
#define NQH     32
#define NKVH    8
#define DH      128
#define QKV_LD  6144      // (32+16)*128
#define SCALE_F 0.08838834764831845f
// softmax in log2 domain: s' = s * SCALE * log2(e)
#define C2F (0.08838834764831845f * 1.4426950408889634f)

using f32x4  = __attribute__((ext_vector_type(4))) float;
using f32x16 = __attribute__((ext_vector_type(16))) float;
using bf16x8 = __attribute__((ext_vector_type(8))) __bf16;
using u32x2  = __attribute__((ext_vector_type(2))) unsigned;

#define GLOAD_LDS16(gp, lp)                                                   \
  __builtin_amdgcn_global_load_lds(                                           \
      (__attribute__((address_space(1))) const void*)(gp),                    \
      (__attribute__((address_space(3))) void*)(lp), 16, 0, 0)

__device__ __forceinline__ unsigned short f2bf_bits(float f) {
  __hip_bfloat16 b = __float2bfloat16(f);
  return __builtin_bit_cast(unsigned short, b);
}

// permlane32_swap: X[32..63] <-> Y[0..31].
__device__ __forceinline__ void plswap(unsigned& x, unsigned& y) {
  u32x2 r = __builtin_amdgcn_permlane32_swap(x, y, false, false);
  x = r[0];
  y = r[1];
}
// value of the partner lane (l ^ 32)
__device__ __forceinline__ float xhalf(float v, int hiP) {
  unsigned u = __builtin_bit_cast(unsigned, v);
  u32x2 r = __builtin_amdgcn_permlane32_swap(u, u, false, false);
  return __builtin_bit_cast(float, hiP ? r[0] : r[1]);
}

// ---------------------------------------------------------------------------
// Fragment-pack one 8-element chunk of a weight matrix W[N][K=4096] (f32)
// into the GEMM's direct-B layout:
//   dst[(((c*64 + kt)*2 + ks)*16 + g16)*512 + (slot*16 + lr)*8 + j]
//     = W[c*256 + g16*16 + lr][kt*64 + ks*32 + slot*8 + j]
// cid bits (slot fastest): slot=cid&3, lr=(cid>>2)&15, g16=(cid>>6)&15,
// ks=(cid>>10)&1, kt=(cid>>11)&63, c=cid>>17.
// Consecutive threads: 4 slots of one row = 128 B contiguous reads; a wave
// covers one (c,kt,ks,g16) block = contiguous 1 KB writes.
// ---------------------------------------------------------------------------
__device__ __forceinline__ void pack_w_chunk(const float* __restrict__ src,
                                             __hip_bfloat16* __restrict__ dst,
                                             int cid) {
  const int slot = cid & 3;
  const int lr   = (cid >> 2) & 15;
  const int g16  = (cid >> 6) & 15;
  const int ks   = (cid >> 10) & 1;
  const int kt   = (cid >> 11) & 63;
  const int c    = cid >> 17;
  const int n = c * 256 + g16 * 16 + lr;
  const int k = (kt << 6) + (ks << 5) + (slot << 3);
  const float4* s = (const float4*)(src + (size_t)n * 4096 + k);
  float4 v0 = s[0], v1 = s[1];
  ushort4 a, b;
  a.x = f2bf_bits(v0.x); a.y = f2bf_bits(v0.y);
  a.z = f2bf_bits(v0.z); a.w = f2bf_bits(v0.w);
  b.x = f2bf_bits(v1.x); b.y = f2bf_bits(v1.y);
  b.z = f2bf_bits(v1.z); b.w = f2bf_bits(v1.w);
  size_t off = ((size_t)(((c * 64 + kt) * 2 + ks) * 16 + g16)) * 512 +
               (slot * 16 + lr) * 8;
  *(ushort4*)(dst + off)     = a;
  *(ushort4*)(dst + off + 4) = b;
}

// ---------------------------------------------------------------------------
// hs f32->bf16 (linear, A-side) + wqkv fragment-pack (B-side)
// ---------------------------------------------------------------------------
__global__ void cvt2_kernel(const float* __restrict__ hs,
                            __hip_bfloat16* __restrict__ hsb,
                            const float* __restrict__ wq,
                            __hip_bfloat16* __restrict__ wqb) {
  const int NHS = (S_SEQ * HID) / 4;       // float4 chunks of hs
  const int NWQP = (QKV_LD * HID) / 8;     // 8-el pack chunks of wqkv
  int i = blockIdx.x * blockDim.x + threadIdx.x;
  int stride = gridDim.x * blockDim.x;
  for (int e = i; e < NHS + NWQP; e += stride) {
    if (e < NHS) {
      float4 v = ((const float4*)hs)[e];
      ushort4 u;
      u.x = f2bf_bits(v.x); u.y = f2bf_bits(v.y);
      u.z = f2bf_bits(v.z); u.w = f2bf_bits(v.w);
      ((ushort4*)hsb)[e] = u;
    } else {
      pack_w_chunk(wq, wqb, e - NHS);
    }
  }
}

// ---------------------------------------------------------------------------
// GEMM: C[M,N] = A[M,K] * B_packed   (A bf16 row-major, B fragment-packed)
// Tile (MF*32) x 256, BK=64, 8 waves, 512 threads.
//  - A through LDS (gload_lds, double-buffered, slot swizzle as before)
//  - B read DIRECTLY from global fragment-packed layout (L2-resident panels),
//    prefetched one full phase ahead into registers bA/bB (static indexing)
//  - counted waits: vmcnt(6) for MF=8 / vmcnt(5) for MF=4 (2 or 1 A-issues +
//    4 B-loads per phase); prologue ordered A00,B00,A01,B01; drain at end
//  - s_setprio around MFMA clusters; bijective XCD swizzle; column-major
//    wgid decode for B-panel L2 sharing
//  - FUSE: grid-x blocks >= nbx_main fragment-pack wo on idle CUs
// ---------------------------------------------------------------------------
template <bool OUT_BF16, int MF, bool FUSE>
__global__ __launch_bounds__(512) void gemm_bt_kernel(
    const __hip_bfloat16* __restrict__ A, const __hip_bfloat16* __restrict__ Bf,
    void* __restrict__ Cv, int M, int N, int K, int nbx_main,
    const float* __restrict__ csrc, __hip_bfloat16* __restrict__ cdst,
    int cnchunks) {
  extern __shared__ __hip_bfloat16 sAB[];
  constexpr int A_BUF = MF * 2048;       // elements of A per buffer
  constexpr int A_KS  = MF * 1024;       // elements per k-slice of A
  const int tid = threadIdx.x;

  if (FUSE) {
    if ((int)blockIdx.x >= nbx_main) {
      const int nb = gridDim.x - nbx_main;
      const int cid0 = ((int)blockIdx.x - nbx_main) + (int)blockIdx.y * nb;
      const int stride = nb * gridDim.y * 512;
      for (int e = cid0 * 512 + tid; e < cnchunks; e += stride)
        pack_w_chunk(csrc, cdst, e);
      return;
    }
  }

  const int w = tid >> 6, l = tid & 63;
  const int wm = w >> 2, wn = w & 3;
  const int lr = l & 15;

  const int nbx = nbx_main;
  const int gdy = gridDim.y;
  const int nwg = nbx * gdy;
  int wgid = blockIdx.y * nbx + blockIdx.x;
  wgid = (wgid & 7) * (nwg >> 3) + (wgid >> 3);  // XCD chunking
  const int bx = wgid / gdy;   // column-major: chunk shares B panels
  const int by = wgid % gdy;
  const int brow = by * (MF * 32);
  const int bcol = bx * 256;

  f32x4 acc[MF][4];
#pragma unroll
  for (int m = 0; m < MF; m++)
#pragma unroll
    for (int n = 0; n < 4; n++) acc[m][n] = (f32x4){0.f, 0.f, 0.f, 0.f};

  // A staging (unchanged): linear LDS dest + inverse-permuted source
  const int r0 = tid >> 2;
  const int c0s = (((tid & 3) ^ ((tid >> 3) & 3)) << 3);
  const __hip_bfloat16* Ag = A + (size_t)(brow + r0) * K + c0s;
  const int ldst = tid * 8;
  const int sw8 = (((l >> 4) ^ ((lr >> 1) & 3)) << 3);

  // B fragment base: per (kt,ks,g4): off = ((kt*2+ks)*16 + wn*4+g4)*512
  const __hip_bfloat16* Bfb = Bf + ((size_t)bx * 64 * 2 * 16) * 512 + l * 8;

#define STG_A(BUF, K0, KS, RB)                                                \
  GLOAD_LDS16(Ag + (K0) + (KS) * 32 + (size_t)((RB) * 128) * K,               \
              sAB + (BUF) * (2 * A_BUF / 2) + (KS) * A_KS + (RB) * 4096 + ldst)
#define STG_A_ALL(BUF, K0, KS)                                                \
  {                                                                           \
    STG_A(BUF, K0, KS, 0);                                                    \
    if constexpr (MF == 8) STG_A(BUF, K0, KS, 1);                             \
  }
#define LOAD_B(BR, T, KS)                                                     \
  {                                                                           \
    _Pragma("unroll") for (int g4 = 0; g4 < 4; g4++) BR[g4] =                 \
        *(const bf16x8*)(Bfb +                                                \
                         (size_t)((((T)*2 + (KS)) * 16 + wn * 4 + g4)) * 512);\
  }
#define WAIT_L()                                                              \
  {                                                                           \
    if constexpr (MF == 8)                                                    \
      asm volatile("s_waitcnt vmcnt(6)" ::: "memory");                        \
    else                                                                      \
      asm volatile("s_waitcnt vmcnt(5)" ::: "memory");                        \
  }
#define CLUSTER(BR, NP)                                                       \
  {                                                                           \
    __builtin_amdgcn_s_setprio(1);                                            \
    _Pragma("unroll") for (int mm = 0; mm < MF; mm++)                         \
        _Pragma("unroll") for (int j = 0; j < 2; j++)                         \
        acc[mm][(NP)*2 + j] = __builtin_amdgcn_mfma_f32_16x16x32_bf16(        \
            af[mm], BR[(NP)*2 + j], acc[mm][(NP)*2 + j], 0, 0, 0);            \
    __builtin_amdgcn_s_setprio(0);                                            \
  }

  bf16x8 bA[4], bB[4];
  const int nt = K >> 6;  // 64 K-tiles
  // prologue (order matters for vmcnt counting): A00, B00, A01, B01
  STG_A_ALL(0, 0, 0);
  LOAD_B(bA, 0, 0);
  STG_A_ALL(0, 0, 1);
  LOAD_B(bB, 0, 1);

  for (int t = 0; t < nt; ++t) {
    const int buf = t & 1, nb2 = buf ^ 1;
    const int k1 = (t + 1) << 6;
    const bool hn = (t + 1) < nt;
    const __hip_bfloat16* ab0 = sAB + buf * A_BUF;

    // ---- phase 0 (uses A(t,ks0) LDS + bA regs) ----
    WAIT_L();
    __builtin_amdgcn_s_barrier();
    __builtin_amdgcn_sched_barrier(0);
    if (hn) STG_A_ALL(nb2, k1, 0);
    {
      bf16x8 af[MF];
#pragma unroll
      for (int mm = 0; mm < MF; mm++)
        af[mm] = *(const bf16x8*)&ab0[(wm * MF * 16 + mm * 16 + lr) * 32 + sw8];
      CLUSTER(bA, 0);
      CLUSTER(bA, 1);
    }
    if (hn) LOAD_B(bA, t + 1, 0);
    // ---- phase 1 (uses A(t,ks1) LDS + bB regs) ----
    if (hn) {
      WAIT_L();
    } else {
      asm volatile("s_waitcnt vmcnt(0)" ::: "memory");
    }
    __builtin_amdgcn_s_barrier();
    __builtin_amdgcn_sched_barrier(0);
    if (hn) STG_A_ALL(nb2, k1, 1);
    {
      const __hip_bfloat16* ab1 = ab0 + A_KS;
      bf16x8 af[MF];
#pragma unroll
      for (int mm = 0; mm < MF; mm++)
        af[mm] = *(const bf16x8*)&ab1[(wm * MF * 16 + mm * 16 + lr) * 32 + sw8];
      CLUSTER(bB, 0);
      CLUSTER(bB, 1);
    }
    if (hn) LOAD_B(bB, t + 1, 1);
  }
#undef STG_A
#undef STG_A_ALL
#undef LOAD_B
#undef WAIT_L
#undef CLUSTER

  const int jr = (l >> 4) << 2;
  if (OUT_BF16) {
    __hip_bfloat16* C = (__hip_bfloat16*)Cv;
#pragma unroll
    for (int m = 0; m < MF; m++)
#pragma unroll
      for (int n = 0; n < 4; n++)
#pragma unroll
        for (int j = 0; j < 4; j++) {
          size_t row = brow + wm * MF * 16 + m * 16 + jr + j;
          size_t col = bcol + wn * 64 + n * 16 + lr;
          C[row * N + col] = __float2bfloat16(acc[m][n][j]);
        }
  } else {
    float* C = (float*)Cv;
#pragma unroll
    for (int m = 0; m < MF; m++)
#pragma unroll
      for (int n = 0; n < 4; n++)
#pragma unroll
        for (int j = 0; j < 4; j++) {
          size_t row = brow + wm * MF * 16 + m * 16 + jr + j;
          size_t col = bcol + wn * 64 + n * 16 + lr;
          C[row * N + col] = acc[m][n][j];
        }
  }
}

// ---------------------------------------------------------------------------
// RoPE (neox) in-place on Q only (heads 0..31); K rope fused into packkv.
// ---------------------------------------------------------------------------
__global__ void ropeq_kernel(__hip_bfloat16* __restrict__ QKV,
                             const int* __restrict__ pos) {
  int idx = blockIdx.x * blockDim.x + threadIdx.x;  // S*32*64 total
  int d = idx & 63;
  int head = (idx >> 6) & 31;
  int s = idx >> 11;
  float p = (float)pos[s];
  float inv = exp2f(-(float)d * 0.2076205059304297f);
  float fr = p * inv;
  float sn, cs;
  sincosf(fr, &sn, &cs);
  size_t base = (size_t)s * QKV_LD + head * 128 + d;
  float x1 = __bfloat162float(QKV[base]);
  float x2 = __bfloat162float(QKV[base + 64]);
  QKV[base]      = __float2bfloat16(x1 * cs - x2 * sn);
  QKV[base + 64] = __float2bfloat16(x2 * cs + x1 * sn);
}

// ---------------------------------------------------------------------------
// Pack K (with fused rope) and V into fragment-ordered buffers for attn.
// ---------------------------------------------------------------------------
__global__ void packkv_kernel(const __hip_bfloat16* __restrict__ QKV,
                              const int* __restrict__ pos,
                              __hip_bfloat16* __restrict__ Kf,
                              __hip_bfloat16* __restrict__ Vf) {
  int o = blockIdx.x * blockDim.x + threadIdx.x;  // 2 * 2^18 chunks
  const int lane = o & 63;
  const int slot = (o >> 6) & 7;
  const int t    = (o >> 9) & 63;
  const int kvh  = (o >> 15) & 7;
  const int off8 = (o & 0x3FFFF) * 8;
  if (o < (1 << 18)) {
    const int s  = t * 32 + (lane & 31);
    const int d0 = slot * 16 + (lane >> 5) * 8;
    const __hip_bfloat16* kb = QKV + (size_t)s * QKV_LD + 4096 + kvh * DH;
    bf16x8 own = *(const bf16x8*)(kb + d0);
    bf16x8 prt = *(const bf16x8*)(kb + (d0 ^ 64));
    float p = (float)pos[s];
    bf16x8 outv;
#pragma unroll
    for (int j = 0; j < 8; j++) {
      float f = (float)((d0 & 63) + j);
      float inv = exp2f(-f * 0.2076205059304297f);
      float sn, cs;
      sincosf(p * inv, &sn, &cs);
      float a = (float)own[j], b = (float)prt[j];
      outv[j] = (__bf16)((d0 < 64) ? (a * cs - b * sn) : (a * cs + b * sn));
    }
    *(bf16x8*)(Kf + off8) = outv;
  } else {
    const int s0 = t * 32 + (slot & 1) * 16 + (lane >> 5) * 8;
    const int d  = (slot >> 1) * 32 + (lane & 31);
    const __hip_bfloat16* src = QKV + (size_t)s0 * QKV_LD + 5120 + kvh * DH + d;
    ushort4 a, b;
    a.x = __builtin_bit_cast(unsigned short, src[0 * QKV_LD]);
    a.y = __builtin_bit_cast(unsigned short, src[1 * QKV_LD]);
    a.z = __builtin_bit_cast(unsigned short, src[2 * QKV_LD]);
    a.w = __builtin_bit_cast(unsigned short, src[3 * QKV_LD]);
    b.x = __builtin_bit_cast(unsigned short, src[4 * QKV_LD]);
    b.y = __builtin_bit_cast(unsigned short, src[5 * QKV_LD]);
    b.z = __builtin_bit_cast(unsigned short, src[6 * QKV_LD]);
    b.w = __builtin_bit_cast(unsigned short, src[7 * QKV_LD]);
    *(ushort4*)(Vf + off8)     = a;
    *(ushort4*)(Vf + off8 + 4) = b;
  }
}

// ---------------------------------------------------------------------------
// Causal GQA flash attention (unchanged): swapped-QK 32x32 + split-KV x2.
// ---------------------------------------------------------------------------
__global__ __launch_bounds__(256, 2) void attn_kernel(
    const __hip_bfloat16* __restrict__ QKV, const __hip_bfloat16* __restrict__ Kf,
    const __hip_bfloat16* __restrict__ Vf, __hip_bfloat16* __restrict__ O) {
  __shared__ float Ms[2][64][67];
  const int tid = threadIdx.x;
  const int w = tid >> 6, l = tid & 63;
  const int l31 = l & 31;
  const int hiP = l >> 5;
  const int bid = blockIdx.x;
  const int kvh = bid & 7;
  const int hp = (bid >> 3) & 1;
  const int qt = 63 - (bid >> 4);
  const int half = w >> 1;
  const int h = kvh * 4 + hp * 2 + (w & 1);
  const int qwb = qt * 32;
  const int qg = qwb + l31;

  const __hip_bfloat16* Qp  = QKV + (size_t)h * DH;
  const __hip_bfloat16* Kfp = Kf + (size_t)kvh * 262144 + l * 8;
  const __hip_bfloat16* Vfp = Vf + (size_t)kvh * 262144 + l * 8;

  bf16x8 qf[8];
  {
    const __hip_bfloat16* qrow = Qp + (size_t)(qwb + l31) * QKV_LD + hiP * 8;
#pragma unroll
    for (int ks = 0; ks < 8; ks++) qf[ks] = *(const bf16x8*)(qrow + ks * 16);
  }

  f32x16 oacc[4];
#pragma unroll
  for (int db = 0; db < 4; db++)
#pragma unroll
    for (int r = 0; r < 16; r++) oacc[db][r] = 0.f;
  float m = -1e30f, lsum = 0.f;

#define COMPUTE_TILE(KB, MASKED)                                               \
  {                                                                            \
    const int kb_ = (KB);                                                      \
    const int toff_ = (kb_ >> 5) * 4096;                                       \
    f32x16 sacc;                                                               \
    _Pragma("unroll") for (int r = 0; r < 16; r++) sacc[r] = 0.f;              \
    {                                                                          \
      bf16x8 kf[8];                                                            \
      _Pragma("unroll") for (int ks = 0; ks < 8; ks++) kf[ks] =                \
          *(const bf16x8*)(Kfp + toff_ + ks * 512);                            \
      _Pragma("unroll") for (int ks = 0; ks < 8; ks++) sacc =                  \
          __builtin_amdgcn_mfma_f32_32x32x16_bf16(kf[ks], qf[ks], sacc, 0, 0,  \
                                                  0);                          \
    }                                                                          \
    bf16x8 vf[4][2];                                                           \
    _Pragma("unroll") for (int db = 0; db < 4; db++)                           \
        _Pragma("unroll") for (int k2 = 0; k2 < 2; k2++) vf[db][k2] =          \
        *(const bf16x8*)(Vfp + toff_ + (db * 2 + k2) * 512);                   \
    float s[16];                                                               \
    _Pragma("unroll") for (int r = 0; r < 16; r++) s[r] = sacc[r] * C2F;       \
    if (MASKED) {                                                              \
      _Pragma("unroll") for (int r = 0; r < 16; r++) {                         \
        const int kvg = kb_ + (r & 3) + 8 * (r >> 2) + 4 * hiP;                \
        s[r] = (kvg <= qg) ? s[r] : -1e30f;                                    \
      }                                                                        \
    }                                                                          \
    float m0 = fmaxf(fmaxf(s[0], s[1]), fmaxf(s[2], s[3]));                    \
    float m1 = fmaxf(fmaxf(s[4], s[5]), fmaxf(s[6], s[7]));                    \
    float m2 = fmaxf(fmaxf(s[8], s[9]), fmaxf(s[10], s[11]));                  \
    float m3 = fmaxf(fmaxf(s[12], s[13]), fmaxf(s[14], s[15]));                \
    float rmax = fmaxf(fmaxf(m0, m1), fmaxf(m2, m3));                          \
    rmax = fmaxf(rmax, xhalf(rmax, hiP));                                      \
    if (__any(rmax - m > 8.0f)) {                                              \
      float mn = fmaxf(m, rmax);                                               \
      float sc = __builtin_amdgcn_exp2f(m - mn);                               \
      lsum *= sc;                                                              \
      _Pragma("unroll") for (int db = 0; db < 4; db++)                         \
          _Pragma("unroll") for (int r = 0; r < 16; r++) oacc[db][r] *= sc;    \
      m = mn;                                                                  \
    }                                                                          \
    float p[16];                                                               \
    _Pragma("unroll") for (int r = 0; r < 16; r++) p[r] =                      \
        __builtin_amdgcn_exp2f(s[r] - m);                                      \
    float rs = ((p[0] + p[1]) + (p[2] + p[3])) +                               \
               ((p[4] + p[5]) + (p[6] + p[7])) +                               \
               ((p[8] + p[9]) + (p[10] + p[11])) +                             \
               ((p[12] + p[13]) + (p[14] + p[15]));                            \
    lsum += rs + xhalf(rs, hiP);                                               \
    unsigned Wp[8];                                                            \
    _Pragma("unroll") for (int i = 0; i < 8; i++) Wp[i] =                      \
        (unsigned)f2bf_bits(p[2 * i]) |                                        \
        ((unsigned)f2bf_bits(p[2 * i + 1]) << 16);                             \
    unsigned s0x = Wp[0], s0y = Wp[2];                                         \
    unsigned s1x = Wp[1], s1y = Wp[3];                                         \
    unsigned s2x = Wp[4], s2y = Wp[6];                                         \
    unsigned s3x = Wp[5], s3y = Wp[7];                                         \
    plswap(s0x, s0y);                                                          \
    plswap(s1x, s1y);                                                          \
    plswap(s2x, s2y);                                                          \
    plswap(s3x, s3y);                                                          \
    int4 f0, f1;                                                               \
    f0.x = (int)s0x; f0.y = (int)s1x; f0.z = (int)s0y; f0.w = (int)s1y;        \
    f1.x = (int)s2x; f1.y = (int)s3x; f1.z = (int)s2y; f1.w = (int)s3y;        \
    bf16x8 pfrag[2];                                                           \
    pfrag[0] = __builtin_bit_cast(bf16x8, f0);                                 \
    pfrag[1] = __builtin_bit_cast(bf16x8, f1);                                 \
    _Pragma("unroll") for (int db = 0; db < 4; db++)                           \
        _Pragma("unroll") for (int k2 = 0; k2 < 2; k2++) oacc[db] =            \
        __builtin_amdgcn_mfma_f32_32x32x16_bf16(vf[db][k2], pfrag[k2],         \
                                                oacc[db], 0, 0, 0);            \
  }

  const int nt = qt + 1;
  const int nt0 = nt >> 1;

  if (half) {
    for (int kb = nt0 * 32; kb < qwb; kb += 32) COMPUTE_TILE(kb, false);
    COMPUTE_TILE(qwb, true);
  } else {
    const int kend = nt0 * 32;
    for (int kb = 0; kb < kend; kb += 32) COMPUTE_TILE(kb, false);
  }
#undef COMPUTE_TILE

  if (half) {
    float* dst = Ms[w & 1][l];
#pragma unroll
    for (int db = 0; db < 4; db++)
#pragma unroll
      for (int r = 0; r < 16; r++) dst[db * 16 + r] = oacc[db][r];
    dst[64] = m;
    dst[65] = lsum;
  }
  __syncthreads();
  if (!half) {
    const float* src = Ms[w & 1][l];
    const float mB = src[64], lB = src[65];
    const float mS = fmaxf(m, mB);
    float fa = __builtin_amdgcn_exp2f(m - mS);
    float fb = __builtin_amdgcn_exp2f(mB - mS);
    const float inv = 1.0f / (lsum * fa + lB * fb);
    fa *= inv;
    fb *= inv;
    __hip_bfloat16* orow = O + (size_t)qg * (NQH * DH) + h * DH;
#pragma unroll
    for (int db = 0; db < 4; db++)
#pragma unroll
      for (int rg = 0; rg < 4; rg++) {
        ushort4 u;
        u.x = f2bf_bits(oacc[db][rg * 4 + 0] * fa + src[db * 16 + rg * 4 + 0] * fb);
        u.y = f2bf_bits(oacc[db][rg * 4 + 1] * fa + src[db * 16 + rg * 4 + 1] * fb);
        u.z = f2bf_bits(oacc[db][rg * 4 + 2] * fa + src[db * 16 + rg * 4 + 2] * fb);
        u.w = f2bf_bits(oacc[db][rg * 4 + 3] * fa + src[db * 16 + rg * 4 + 3] * fb);
        *reinterpret_cast<ushort4*>(orow + db * 32 + 8 * rg + 4 * hiP) = u;
      }
  }
}

// ---------------------------------------------------------------------------
extern "C" void kernel_launch(void* const* d_in, const int* in_sizes, int n_in,
                              void* d_out, int out_size, void* d_ws,
                              size_t ws_size, hipStream_t stream) {
  const float* hs = (const float*)d_in[0];
  const int* pos = (const int*)d_in[1];
  const float* wqkv = (const float*)d_in[2];
  const float* wo = (const float*)d_in[3];
  float* out = (float*)d_out;

  char* ws = (char*)d_ws;
  __hip_bfloat16* Xb      = (__hip_bfloat16*)(ws);                // 16 MB
  __hip_bfloat16* Wqkvb   = (__hip_bfloat16*)(ws + 16777216);     // 48 MB (packed)
  __hip_bfloat16* Wob     = (__hip_bfloat16*)(ws + 67108864);     // 32 MB (packed)
  __hip_bfloat16* QKV     = (__hip_bfloat16*)(ws + 100663296);    // 24 MB
  __hip_bfloat16* AttnOut = (__hip_bfloat16*)(ws + 125829120);    // 16 MB
  __hip_bfloat16* Kf      = (__hip_bfloat16*)(ws + 142606336);    // 4 MB
  __hip_bfloat16* Vf      = (__hip_bfloat16*)(ws);                // 4 MB (Xb dead after gemm1)

  // hs linear convert + wqkv fragment-pack
  cvt2_kernel<<<2048, 256, 0, stream>>>(hs, Xb, wqkv, Wqkvb);

  // QKV GEMM (blocks x<24) + wo fragment-pack on the 64 idle CUs
  gemm_bt_kernel<true, 8, true>
      <<<dim3(32, 8), 512, 65536, stream>>>(
          Xb, Wqkvb, QKV, S_SEQ, QKV_LD, HID, 24, wo, Wob,
          (HID * HID) / 8);

  ropeq_kernel<<<(S_SEQ * 32 * 64) / 256, 256, 0, stream>>>(QKV, pos);
  packkv_kernel<<<2048, 256, 0, stream>>>(QKV, pos, Kf, Vf);

  attn_kernel<<<1024, 256, 0, stream>>>(QKV, Kf, Vf, AttnOut);

  gemm_bt_kernel<false, 4, false>
      <<<dim3(16, 16), 512, 32768, stream>>>(
          AttnOut, Wob, out, S_SEQ, HID, HID, 16, nullptr, nullptr, 0);
}

// Round 18
// 291.178 us; speedup vs baseline: 1.1724x; 1.0418x over previous
//
#include <hip/hip_runtime.h>
#include <hip/hip_bf16.h>
#include <cstdint>

#define S_SEQ   2048
#define HID     4096
#define NQH     32
#define NKVH    8
#define DH      128
#define QKV_LD  6144      // (32+16)*128
#define SCALE_F 0.08838834764831845f
// softmax in log2 domain: s' = s * SCALE * log2(e)
#define C2F (0.08838834764831845f * 1.4426950408889634f)

using f32x4  = __attribute__((ext_vector_type(4))) float;
using f32x16 = __attribute__((ext_vector_type(16))) float;
using bf16x8 = __attribute__((ext_vector_type(8))) __bf16;
using u32x2  = __attribute__((ext_vector_type(2))) unsigned;

#define GLOAD_LDS16(gp, lp)                                                   \
  __builtin_amdgcn_global_load_lds(                                           \
      (__attribute__((address_space(1))) const void*)(gp),                    \
      (__attribute__((address_space(3))) void*)(lp), 16, 0, 0)

__device__ __forceinline__ unsigned short f2bf_bits(float f) {
  __hip_bfloat16 b = __float2bfloat16(f);
  return __builtin_bit_cast(unsigned short, b);
}

// permlane32_swap: X[32..63] <-> Y[0..31].
__device__ __forceinline__ void plswap(unsigned& x, unsigned& y) {
  u32x2 r = __builtin_amdgcn_permlane32_swap(x, y, false, false);
  x = r[0];
  y = r[1];
}
// value of the partner lane (l ^ 32)
__device__ __forceinline__ float xhalf(float v, int hiP) {
  unsigned u = __builtin_bit_cast(unsigned, v);
  u32x2 r = __builtin_amdgcn_permlane32_swap(u, u, false, false);
  return __builtin_bit_cast(float, hiP ? r[0] : r[1]);
}

// ---------------------------------------------------------------------------
// merged f32 -> bf16 conversion for hs + wqkv (single kernel, fewer tails)
// ---------------------------------------------------------------------------
__global__ void cvt2_kernel(const float* __restrict__ hs,
                            __hip_bfloat16* __restrict__ hsb,
                            const float* __restrict__ wq,
                            __hip_bfloat16* __restrict__ wqb) {
  const int NHS = (S_SEQ * HID) / 4;     // 2,097,152 float4
  const int NWQ = (QKV_LD * HID) / 4;    // 6,291,456 float4
  int i = blockIdx.x * blockDim.x + threadIdx.x;
  int stride = gridDim.x * blockDim.x;
  for (int e = i; e < NHS + NWQ; e += stride) {
    const float4* src;
    ushort4* dst;
    int idx;
    if (e < NHS) {
      src = (const float4*)hs; dst = (ushort4*)hsb; idx = e;
    } else {
      src = (const float4*)wq; dst = (ushort4*)wqb; idx = e - NHS;
    }
    float4 v = src[idx];
    ushort4 u;
    u.x = f2bf_bits(v.x); u.y = f2bf_bits(v.y);
    u.z = f2bf_bits(v.z); u.w = f2bf_bits(v.w);
    dst[idx] = u;
  }
}

// ---------------------------------------------------------------------------
// GEMM: C[M,N] = A[M,K] * B[N,K]^T   (both bf16, B^T layout)
// Tile (MF*32) x 256, BK=64, 8 waves, 512 threads. 4-phase fine-interleaved
// schedule (ks x n-half), LDS double-buffered:
//  - per phase: {ds_read this phase's frags; issue ONE stage-group (t+1);
//    lgkmcnt(0)+sched_barrier; setprio(1) 16-MFMA cluster setprio(0);
//    [counted vmcnt at ph1/ph3]; s_barrier}
//  - A-frags held in regs across the ks's two phases: LDS reads unchanged
//  - groups g0=A-ks0, g1=B-ks0, g2=A-ks1, g3=B-ks1; uniform vmcnt(4) (MF=8)
//    / vmcnt(3) (MF=4): forces exactly the two groups the next phase needs
//  - slot swizzle (slot ^= (row>>1)&3) linear-dest + inverse-permuted source
//  - bijective XCD swizzle; column-major wgid decode (B-panel L2 sharing)
//  - FUSE: grid-x blocks >= nbx_main run the wo f32->bf16 convert
// ---------------------------------------------------------------------------
template <bool OUT_BF16, int MF, bool FUSE>
__global__ __launch_bounds__(512) void gemm_bt_kernel(
    const __hip_bfloat16* __restrict__ A, const __hip_bfloat16* __restrict__ B,
    void* __restrict__ Cv, int M, int N, int K, int nbx_main,
    const float* __restrict__ csrc, __hip_bfloat16* __restrict__ cdst,
    int cn4) {
  extern __shared__ __hip_bfloat16 sAB[];
  constexpr int A_BUF = MF * 2048;       // elements of A per buffer
  constexpr int A_KS  = MF * 1024;       // elements per k-slice of A
  constexpr int BUFSZ = A_BUF + 16384;   // + B (256 rows x 32 el) x 2 slices
  const int tid = threadIdx.x;

  if (FUSE) {
    if ((int)blockIdx.x >= nbx_main) {
      const int nb = gridDim.x - nbx_main;
      const int cid = ((int)blockIdx.x - nbx_main) + (int)blockIdx.y * nb;
      const int stride = nb * gridDim.y * 512;
      for (int e = cid * 512 + tid; e < cn4; e += stride) {
        float4 v = ((const float4*)csrc)[e];
        ushort4 u;
        u.x = f2bf_bits(v.x); u.y = f2bf_bits(v.y);
        u.z = f2bf_bits(v.z); u.w = f2bf_bits(v.w);
        ((ushort4*)cdst)[e] = u;
      }
      return;
    }
  }

  const int w = tid >> 6, l = tid & 63;
  const int wm = w >> 2, wn = w & 3;
  const int lr = l & 15;

  const int nbx = nbx_main;
  const int gdy = gridDim.y;
  const int nwg = nbx * gdy;
  int wgid = blockIdx.y * nbx + blockIdx.x;
  wgid = (wgid & 7) * (nwg >> 3) + (wgid >> 3);  // XCD chunking
  const int bx = wgid / gdy;   // column-major: chunk shares B panels
  const int by = wgid % gdy;
  const int brow = by * (MF * 32);
  const int bcol = bx * 256;

  f32x4 acc[MF][4];
#pragma unroll
  for (int m = 0; m < MF; m++)
#pragma unroll
    for (int n = 0; n < 4; n++) acc[m][n] = (f32x4){0.f, 0.f, 0.f, 0.f};

  const int r0 = tid >> 2;                                  // 0..127
  const int c0s = (((tid & 3) ^ ((tid >> 3) & 3)) << 3);    // elements
  const __hip_bfloat16* Ag = A + (size_t)(brow + r0) * K + c0s;
  const __hip_bfloat16* Bg = B + (size_t)(bcol + r0) * K + c0s;
  const int ldst = tid * 8;

  const int sw8 = (((l >> 4) ^ ((lr >> 1) & 3)) << 3);

#define STG_A(BUF, K0, KS, RB)                                                \
  GLOAD_LDS16(Ag + (K0) + (KS) * 32 + (size_t)((RB) * 128) * K,               \
              sAB + (BUF) * BUFSZ + (KS) * A_KS + (RB) * 4096 + ldst)
#define STG_B(BUF, K0, KS, RB)                                                \
  GLOAD_LDS16(Bg + (K0) + (KS) * 32 + (size_t)((RB) * 128) * K,               \
              sAB + (BUF) * BUFSZ + A_BUF + (KS) * 8192 + (RB) * 4096 + ldst)
#define STG_G0(BUF, K0)                                                       \
  {                                                                           \
    STG_A(BUF, K0, 0, 0);                                                     \
    if constexpr (MF == 8) STG_A(BUF, K0, 0, 1);                              \
  }
#define STG_G1(BUF, K0) { STG_B(BUF, K0, 0, 0); STG_B(BUF, K0, 0, 1); }
#define STG_G2(BUF, K0)                                                       \
  {                                                                           \
    STG_A(BUF, K0, 1, 0);                                                     \
    if constexpr (MF == 8) STG_A(BUF, K0, 1, 1);                              \
  }
#define STG_G3(BUF, K0) { STG_B(BUF, K0, 1, 0); STG_B(BUF, K0, 1, 1); }

#define WAIT_L()                                                              \
  {                                                                           \
    if constexpr (MF == 8)                                                    \
      asm volatile("s_waitcnt vmcnt(4)" ::: "memory");                        \
    else                                                                      \
      asm volatile("s_waitcnt vmcnt(3)" ::: "memory");                        \
  }
#define LGKM()                                                                \
  {                                                                           \
    asm volatile("s_waitcnt lgkmcnt(0)" ::: "memory");                        \
    __builtin_amdgcn_sched_barrier(0);                                        \
  }
// 16-MFMA cluster into acc[.][NH*2 + j]
#define CLUSTER(NH)                                                           \
  {                                                                           \
    __builtin_amdgcn_s_setprio(1);                                            \
    _Pragma("unroll") for (int mm = 0; mm < MF; mm++)                         \
        _Pragma("unroll") for (int j = 0; j < 2; j++)                         \
        acc[mm][(NH)*2 + j] = __builtin_amdgcn_mfma_f32_16x16x32_bf16(        \
            af[mm], bfr[j], acc[mm][(NH)*2 + j], 0, 0, 0);                    \
    __builtin_amdgcn_s_setprio(0);                                            \
  }

  const int nt = K >> 6;  // 64 K-tiles
  // prologue: all 4 groups of tile 0; wait g0,g1 (leaves g2,g3 in flight)
  STG_G0(0, 0); STG_G1(0, 0); STG_G2(0, 0); STG_G3(0, 0);
  WAIT_L();
  __builtin_amdgcn_s_barrier();

  for (int t = 0; t < nt; ++t) {
    const int buf = t & 1, nb2 = buf ^ 1;
    const int k1 = (t + 1) << 6;
    const bool hn = (t + 1) < nt;
    const __hip_bfloat16* ab = sAB + buf * BUFSZ;
    const __hip_bfloat16* bb = ab + A_BUF;
    const __hip_bfloat16* ab1 = ab + A_KS;
    const __hip_bfloat16* bb1 = bb + 8192;
    bf16x8 af[MF], bfr[2];

    // ---- ph0: ks0, n-half 0 ----
#pragma unroll
    for (int mm = 0; mm < MF; mm++)
      af[mm] = *(const bf16x8*)&ab[(wm * MF * 16 + mm * 16 + lr) * 32 + sw8];
#pragma unroll
    for (int j = 0; j < 2; j++)
      bfr[j] = *(const bf16x8*)&bb[(wn * 64 + j * 16 + lr) * 32 + sw8];
    if (hn) STG_G0(nb2, k1);
    LGKM();
    CLUSTER(0);
    __builtin_amdgcn_s_barrier();

    // ---- ph1: ks0, n-half 1 ----
#pragma unroll
    for (int j = 0; j < 2; j++)
      bfr[j] = *(const bf16x8*)&bb[(wn * 64 + (2 + j) * 16 + lr) * 32 + sw8];
    if (hn) STG_G1(nb2, k1);
    LGKM();
    CLUSTER(1);
    if (hn) {
      WAIT_L();   // forces g2,g3 of tile t (leaves g0',g1')
    } else {
      asm volatile("s_waitcnt vmcnt(0)" ::: "memory");
    }
    __builtin_amdgcn_s_barrier();

    // ---- ph2: ks1, n-half 0 ----
#pragma unroll
    for (int mm = 0; mm < MF; mm++)
      af[mm] = *(const bf16x8*)&ab1[(wm * MF * 16 + mm * 16 + lr) * 32 + sw8];
#pragma unroll
    for (int j = 0; j < 2; j++)
      bfr[j] = *(const bf16x8*)&bb1[(wn * 64 + j * 16 + lr) * 32 + sw8];
    if (hn) STG_G2(nb2, k1);
    LGKM();
    CLUSTER(0);
    __builtin_amdgcn_s_barrier();

    // ---- ph3: ks1, n-half 1 ----
#pragma unroll
    for (int j = 0; j < 2; j++)
      bfr[j] = *(const bf16x8*)&bb1[(wn * 64 + (2 + j) * 16 + lr) * 32 + sw8];
    if (hn) STG_G3(nb2, k1);
    LGKM();
    CLUSTER(1);
    if (hn) {
      WAIT_L();   // forces g0',g1' of tile t+1 (leaves g2',g3')
    }
    __builtin_amdgcn_s_barrier();
  }
#undef STG_A
#undef STG_B
#undef STG_G0
#undef STG_G1
#undef STG_G2
#undef STG_G3
#undef WAIT_L
#undef LGKM
#undef CLUSTER

  const int jr = (l >> 4) << 2;
  if (OUT_BF16) {
    __hip_bfloat16* C = (__hip_bfloat16*)Cv;
#pragma unroll
    for (int m = 0; m < MF; m++)
#pragma unroll
      for (int n = 0; n < 4; n++)
#pragma unroll
        for (int j = 0; j < 4; j++) {
          size_t row = brow + wm * MF * 16 + m * 16 + jr + j;
          size_t col = bcol + wn * 64 + n * 16 + lr;
          C[row * N + col] = __float2bfloat16(acc[m][n][j]);
        }
  } else {
    float* C = (float*)Cv;
#pragma unroll
    for (int m = 0; m < MF; m++)
#pragma unroll
      for (int n = 0; n < 4; n++)
#pragma unroll
        for (int j = 0; j < 4; j++) {
          size_t row = brow + wm * MF * 16 + m * 16 + jr + j;
          size_t col = bcol + wn * 64 + n * 16 + lr;
          C[row * N + col] = acc[m][n][j];
        }
  }
}

// ---------------------------------------------------------------------------
// RoPE (neox) in-place on Q only (heads 0..31); K rope fused into packkv.
// ---------------------------------------------------------------------------
__global__ void ropeq_kernel(__hip_bfloat16* __restrict__ QKV,
                             const int* __restrict__ pos) {
  int idx = blockIdx.x * blockDim.x + threadIdx.x;  // S*32*64 total
  int d = idx & 63;
  int head = (idx >> 6) & 31;
  int s = idx >> 11;
  float p = (float)pos[s];
  float inv = exp2f(-(float)d * 0.2076205059304297f);
  float fr = p * inv;
  float sn, cs;
  sincosf(fr, &sn, &cs);
  size_t base = (size_t)s * QKV_LD + head * 128 + d;
  float x1 = __bfloat162float(QKV[base]);
  float x2 = __bfloat162float(QKV[base + 64]);
  QKV[base]      = __float2bfloat16(x1 * cs - x2 * sn);
  QKV[base + 64] = __float2bfloat16(x2 * cs + x1 * sn);
}

// ---------------------------------------------------------------------------
// Pack K (with fused rope) and V into fragment-ordered buffers for attn.
// ---------------------------------------------------------------------------
__global__ void packkv_kernel(const __hip_bfloat16* __restrict__ QKV,
                              const int* __restrict__ pos,
                              __hip_bfloat16* __restrict__ Kf,
                              __hip_bfloat16* __restrict__ Vf) {
  int o = blockIdx.x * blockDim.x + threadIdx.x;  // 2 * 2^18 chunks
  const int lane = o & 63;
  const int slot = (o >> 6) & 7;
  const int t    = (o >> 9) & 63;
  const int kvh  = (o >> 15) & 7;
  const int off8 = (o & 0x3FFFF) * 8;
  if (o < (1 << 18)) {
    const int s  = t * 32 + (lane & 31);
    const int d0 = slot * 16 + (lane >> 5) * 8;
    const __hip_bfloat16* kb = QKV + (size_t)s * QKV_LD + 4096 + kvh * DH;
    bf16x8 own = *(const bf16x8*)(kb + d0);
    bf16x8 prt = *(const bf16x8*)(kb + (d0 ^ 64));
    float p = (float)pos[s];
    bf16x8 outv;
#pragma unroll
    for (int j = 0; j < 8; j++) {
      float f = (float)((d0 & 63) + j);
      float inv = exp2f(-f * 0.2076205059304297f);
      float sn, cs;
      sincosf(p * inv, &sn, &cs);
      float a = (float)own[j], b = (float)prt[j];
      outv[j] = (__bf16)((d0 < 64) ? (a * cs - b * sn) : (a * cs + b * sn));
    }
    *(bf16x8*)(Kf + off8) = outv;
  } else {
    const int s0 = t * 32 + (slot & 1) * 16 + (lane >> 5) * 8;
    const int d  = (slot >> 1) * 32 + (lane & 31);
    const __hip_bfloat16* src = QKV + (size_t)s0 * QKV_LD + 5120 + kvh * DH + d;
    ushort4 a, b;
    a.x = __builtin_bit_cast(unsigned short, src[0 * QKV_LD]);
    a.y = __builtin_bit_cast(unsigned short, src[1 * QKV_LD]);
    a.z = __builtin_bit_cast(unsigned short, src[2 * QKV_LD]);
    a.w = __builtin_bit_cast(unsigned short, src[3 * QKV_LD]);
    b.x = __builtin_bit_cast(unsigned short, src[4 * QKV_LD]);
    b.y = __builtin_bit_cast(unsigned short, src[5 * QKV_LD]);
    b.z = __builtin_bit_cast(unsigned short, src[6 * QKV_LD]);
    b.w = __builtin_bit_cast(unsigned short, src[7 * QKV_LD]);
    *(ushort4*)(Vf + off8)     = a;
    *(ushort4*)(Vf + off8 + 4) = b;
  }
}

// ---------------------------------------------------------------------------
// Causal GQA flash attention (unchanged): swapped-QK 32x32 + split-KV x2.
// ---------------------------------------------------------------------------
__global__ __launch_bounds__(256, 2) void attn_kernel(
    const __hip_bfloat16* __restrict__ QKV, const __hip_bfloat16* __restrict__ Kf,
    const __hip_bfloat16* __restrict__ Vf, __hip_bfloat16* __restrict__ O) {
  __shared__ float Ms[2][64][67];
  const int tid = threadIdx.x;
  const int w = tid >> 6, l = tid & 63;
  const int l31 = l & 31;
  const int hiP = l >> 5;
  const int bid = blockIdx.x;
  const int kvh = bid & 7;
  const int hp = (bid >> 3) & 1;
  const int qt = 63 - (bid >> 4);
  const int half = w >> 1;
  const int h = kvh * 4 + hp * 2 + (w & 1);
  const int qwb = qt * 32;
  const int qg = qwb + l31;

  const __hip_bfloat16* Qp  = QKV + (size_t)h * DH;
  const __hip_bfloat16* Kfp = Kf + (size_t)kvh * 262144 + l * 8;
  const __hip_bfloat16* Vfp = Vf + (size_t)kvh * 262144 + l * 8;

  bf16x8 qf[8];
  {
    const __hip_bfloat16* qrow = Qp + (size_t)(qwb + l31) * QKV_LD + hiP * 8;
#pragma unroll
    for (int ks = 0; ks < 8; ks++) qf[ks] = *(const bf16x8*)(qrow + ks * 16);
  }

  f32x16 oacc[4];
#pragma unroll
  for (int db = 0; db < 4; db++)
#pragma unroll
    for (int r = 0; r < 16; r++) oacc[db][r] = 0.f;
  float m = -1e30f, lsum = 0.f;

#define COMPUTE_TILE(KB, MASKED)                                               \
  {                                                                            \
    const int kb_ = (KB);                                                      \
    const int toff_ = (kb_ >> 5) * 4096;                                       \
    f32x16 sacc;                                                               \
    _Pragma("unroll") for (int r = 0; r < 16; r++) sacc[r] = 0.f;              \
    {                                                                          \
      bf16x8 kf[8];                                                            \
      _Pragma("unroll") for (int ks = 0; ks < 8; ks++) kf[ks] =                \
          *(const bf16x8*)(Kfp + toff_ + ks * 512);                            \
      _Pragma("unroll") for (int ks = 0; ks < 8; ks++) sacc =                  \
          __builtin_amdgcn_mfma_f32_32x32x16_bf16(kf[ks], qf[ks], sacc, 0, 0,  \
                                                  0);                          \
    }                                                                          \
    bf16x8 vf[4][2];                                                           \
    _Pragma("unroll") for (int db = 0; db < 4; db++)                           \
        _Pragma("unroll") for (int k2 = 0; k2 < 2; k2++) vf[db][k2] =          \
        *(const bf16x8*)(Vfp + toff_ + (db * 2 + k2) * 512);                   \
    float s[16];                                                               \
    _Pragma("unroll") for (int r = 0; r < 16; r++) s[r] = sacc[r] * C2F;       \
    if (MASKED) {                                                              \
      _Pragma("unroll") for (int r = 0; r < 16; r++) {                         \
        const int kvg = kb_ + (r & 3) + 8 * (r >> 2) + 4 * hiP;                \
        s[r] = (kvg <= qg) ? s[r] : -1e30f;                                    \
      }                                                                        \
    }                                                                          \
    float m0 = fmaxf(fmaxf(s[0], s[1]), fmaxf(s[2], s[3]));                    \
    float m1 = fmaxf(fmaxf(s[4], s[5]), fmaxf(s[6], s[7]));                    \
    float m2 = fmaxf(fmaxf(s[8], s[9]), fmaxf(s[10], s[11]));                  \
    float m3 = fmaxf(fmaxf(s[12], s[13]), fmaxf(s[14], s[15]));                \
    float rmax = fmaxf(fmaxf(m0, m1), fmaxf(m2, m3));                          \
    rmax = fmaxf(rmax, xhalf(rmax, hiP));                                      \
    if (__any(rmax - m > 8.0f)) {                                              \
      float mn = fmaxf(m, rmax);                                               \
      float sc = __builtin_amdgcn_exp2f(m - mn);                               \
      lsum *= sc;                                                              \
      _Pragma("unroll") for (int db = 0; db < 4; db++)                         \
          _Pragma("unroll") for (int r = 0; r < 16; r++) oacc[db][r] *= sc;    \
      m = mn;                                                                  \
    }                                                                          \
    float p[16];                                                               \
    _Pragma("unroll") for (int r = 0; r < 16; r++) p[r] =                      \
        __builtin_amdgcn_exp2f(s[r] - m);                                      \
    float rs = ((p[0] + p[1]) + (p[2] + p[3])) +                               \
               ((p[4] + p[5]) + (p[6] + p[7])) +                               \
               ((p[8] + p[9]) + (p[10] + p[11])) +                             \
               ((p[12] + p[13]) + (p[14] + p[15]));                            \
    lsum += rs + xhalf(rs, hiP);                                               \
    unsigned Wp[8];                                                            \
    _Pragma("unroll") for (int i = 0; i < 8; i++) Wp[i] =                      \
        (unsigned)f2bf_bits(p[2 * i]) |                                        \
        ((unsigned)f2bf_bits(p[2 * i + 1]) << 16);                             \
    unsigned s0x = Wp[0], s0y = Wp[2];                                         \
    unsigned s1x = Wp[1], s1y = Wp[3];                                         \
    unsigned s2x = Wp[4], s2y = Wp[6];                                         \
    unsigned s3x = Wp[5], s3y = Wp[7];                                         \
    plswap(s0x, s0y);                                                          \
    plswap(s1x, s1y);                                                          \
    plswap(s2x, s2y);                                                          \
    plswap(s3x, s3y);                                                          \
    int4 f0, f1;                                                               \
    f0.x = (int)s0x; f0.y = (int)s1x; f0.z = (int)s0y; f0.w = (int)s1y;        \
    f1.x = (int)s2x; f1.y = (int)s3x; f1.z = (int)s2y; f1.w = (int)s3y;        \
    bf16x8 pfrag[2];                                                           \
    pfrag[0] = __builtin_bit_cast(bf16x8, f0);                                 \
    pfrag[1] = __builtin_bit_cast(bf16x8, f1);                                 \
    _Pragma("unroll") for (int db = 0; db < 4; db++)                           \
        _Pragma("unroll") for (int k2 = 0; k2 < 2; k2++) oacc[db] =            \
        __builtin_amdgcn_mfma_f32_32x32x16_bf16(vf[db][k2], pfrag[k2],         \
                                                oacc[db], 0, 0, 0);            \
  }

  const int nt = qt + 1;
  const int nt0 = nt >> 1;

  if (half) {
    for (int kb = nt0 * 32; kb < qwb; kb += 32) COMPUTE_TILE(kb, false);
    COMPUTE_TILE(qwb, true);
  } else {
    const int kend = nt0 * 32;
    for (int kb = 0; kb < kend; kb += 32) COMPUTE_TILE(kb, false);
  }
#undef COMPUTE_TILE

  if (half) {
    float* dst = Ms[w & 1][l];
#pragma unroll
    for (int db = 0; db < 4; db++)
#pragma unroll
      for (int r = 0; r < 16; r++) dst[db * 16 + r] = oacc[db][r];
    dst[64] = m;
    dst[65] = lsum;
  }
  __syncthreads();
  if (!half) {
    const float* src = Ms[w & 1][l];
    const float mB = src[64], lB = src[65];
    const float mS = fmaxf(m, mB);
    float fa = __builtin_amdgcn_exp2f(m - mS);
    float fb = __builtin_amdgcn_exp2f(mB - mS);
    const float inv = 1.0f / (lsum * fa + lB * fb);
    fa *= inv;
    fb *= inv;
    __hip_bfloat16* orow = O + (size_t)qg * (NQH * DH) + h * DH;
#pragma unroll
    for (int db = 0; db < 4; db++)
#pragma unroll
      for (int rg = 0; rg < 4; rg++) {
        ushort4 u;
        u.x = f2bf_bits(oacc[db][rg * 4 + 0] * fa + src[db * 16 + rg * 4 + 0] * fb);
        u.y = f2bf_bits(oacc[db][rg * 4 + 1] * fa + src[db * 16 + rg * 4 + 1] * fb);
        u.z = f2bf_bits(oacc[db][rg * 4 + 2] * fa + src[db * 16 + rg * 4 + 2] * fb);
        u.w = f2bf_bits(oacc[db][rg * 4 + 3] * fa + src[db * 16 + rg * 4 + 3] * fb);
        *reinterpret_cast<ushort4*>(orow + db * 32 + 8 * rg + 4 * hiP) = u;
      }
  }
}

// ---------------------------------------------------------------------------
extern "C" void kernel_launch(void* const* d_in, const int* in_sizes, int n_in,
                              void* d_out, int out_size, void* d_ws,
                              size_t ws_size, hipStream_t stream) {
  const float* hs = (const float*)d_in[0];
  const int* pos = (const int*)d_in[1];
  const float* wqkv = (const float*)d_in[2];
  const float* wo = (const float*)d_in[3];
  float* out = (float*)d_out;

  char* ws = (char*)d_ws;
  __hip_bfloat16* Xb      = (__hip_bfloat16*)(ws);                // 16 MB
  __hip_bfloat16* Wqkvb   = (__hip_bfloat16*)(ws + 16777216);     // 48 MB
  __hip_bfloat16* Wob     = (__hip_bfloat16*)(ws + 67108864);     // 32 MB
  __hip_bfloat16* QKV     = (__hip_bfloat16*)(ws + 100663296);    // 24 MB
  __hip_bfloat16* AttnOut = (__hip_bfloat16*)(ws + 125829120);    // 16 MB
  __hip_bfloat16* Kf      = (__hip_bfloat16*)(ws + 142606336);    // 4 MB
  __hip_bfloat16* Vf      = (__hip_bfloat16*)(ws);                // 4 MB (Xb dead after gemm1)

  // hs + wqkv f32->bf16 (merged)
  cvt2_kernel<<<2048, 256, 0, stream>>>(hs, Xb, wqkv, Wqkvb);

  // QKV GEMM (blocks x<24) + wo f32->bf16 on the 64 otherwise-idle CUs
  gemm_bt_kernel<true, 8, true>
      <<<dim3(32, 8), 512, 131072, stream>>>(
          Xb, Wqkvb, QKV, S_SEQ, QKV_LD, HID, 24, wo, Wob, (HID * HID) / 4);

  ropeq_kernel<<<(S_SEQ * 32 * 64) / 256, 256, 0, stream>>>(QKV, pos);
  packkv_kernel<<<2048, 256, 0, stream>>>(QKV, pos, Kf, Vf);

  attn_kernel<<<1024, 256, 0, stream>>>(QKV, Kf, Vf, AttnOut);

  gemm_bt_kernel<false, 4, false>
      <<<dim3(16, 16), 512, 98304, stream>>>(
          AttnOut, Wob, out, S_SEQ, HID, HID, 16, nullptr, nullptr, 0);
}